// Round 2
// baseline (10691.171 us; speedup 1.0000x reference)
//
#include <hip/hip_runtime.h>
#include <hip/hip_bf16.h>

// Problem constants
#define BB 4
#define LL 2048
#define DD 768
#define DIN 1536
#define NST 16
#define CD 4
#define RR 48

// ---------------------------------------------------------------------------
// LayerNorm over last dim (768). One block (256 thr) per row. Pointers are
// pre-offset to the batch chunk.
__global__ __launch_bounds__(256) void ln_kernel(
    const float* __restrict__ x, const float* __restrict__ g,
    const float* __restrict__ b, float* __restrict__ xn)
{
    int row = blockIdx.x;
    const float* xr = x + (long)row * DD;
    int t = threadIdx.x;
    float v[3];
    float s = 0.f;
#pragma unroll
    for (int i = 0; i < 3; ++i) { v[i] = xr[t + i*256]; s += v[i]; }
#pragma unroll
    for (int off = 32; off >= 1; off >>= 1) s += __shfl_xor(s, off);
    __shared__ float red[4], red2[4];
    int wid = t >> 6;
    if ((t & 63) == 0) red[wid] = s;
    __syncthreads();
    float mean = (red[0]+red[1]+red[2]+red[3]) * (1.f/768.f);
    float vs = 0.f;
#pragma unroll
    for (int i = 0; i < 3; ++i) { float d0 = v[i]-mean; vs += d0*d0; }
#pragma unroll
    for (int off = 32; off >= 1; off >>= 1) vs += __shfl_xor(vs, off);
    if ((t & 63) == 0) red2[wid] = vs;
    __syncthreads();
    float var = (red2[0]+red2[1]+red2[2]+red2[3]) * (1.f/768.f);
    float rstd = rsqrtf(var + 1e-5f);
    float* xo = xn + (long)row * DD;
#pragma unroll
    for (int i = 0; i < 3; ++i) {
        int c = t + i*256;
        xo[c] = (v[i]-mean)*rstd*g[c] + b[c];
    }
}

// ---------------------------------------------------------------------------
// Tiled GEMM: C[m,n] = sum_k A[m,k]*Wacc(n,k) (+bias[n]) (+resid[m,n])
// WMODE=0: Wacc(n,k) = W[n*ldw + k]  (A @ W^T)
// WMODE=1: Wacc(n,k) = W[k*ldw + n]  (A @ W)
// 64x64 tile, BK=16, 256 threads, 4x4 micro-tile per thread. Guarded edges.
template<int WMODE>
__global__ __launch_bounds__(256) void gemm_bt(
    const float* __restrict__ A, const float* __restrict__ W,
    const float* __restrict__ bias, const float* __restrict__ resid,
    float* __restrict__ C,
    int M, int N, int K, int lda, int ldw, int ldc, int ldr)
{
    __shared__ float As[16][65];
    __shared__ float Ws[16][65];
    int bm = blockIdx.y * 64, bn = blockIdx.x * 64;
    int tid = threadIdx.x;
    int lc = tid & 15;       // k within tile for loads
    int lr = tid >> 4;       // 0..15
    int tx = tid & 15, ty = tid >> 4;
    float acc[4][4] = {};
    for (int k0 = 0; k0 < K; k0 += 16) {
        int k = k0 + lc;
        bool kok = (k < K);
#pragma unroll
        for (int i = 0; i < 4; ++i) {
            int m = bm + lr + i*16;
            As[lc][lr + i*16] = (kok && m < M) ? A[(long)m*lda + k] : 0.f;
            int n = bn + lr + i*16;
            float wv = 0.f;
            if (kok && n < N)
                wv = (WMODE == 0) ? W[(long)n*ldw + k] : W[(long)k*ldw + n];
            Ws[lc][lr + i*16] = wv;
        }
        __syncthreads();
#pragma unroll
        for (int kk = 0; kk < 16; ++kk) {
            float a[4], bv[4];
#pragma unroll
            for (int i = 0; i < 4; ++i) a[i]  = As[kk][ty*4+i];
#pragma unroll
            for (int j = 0; j < 4; ++j) bv[j] = Ws[kk][tx*4+j];
#pragma unroll
            for (int i = 0; i < 4; ++i)
#pragma unroll
                for (int j = 0; j < 4; ++j) acc[i][j] += a[i]*bv[j];
        }
        __syncthreads();
    }
#pragma unroll
    for (int i = 0; i < 4; ++i) {
        int m = bm + ty*4 + i;
        if (m >= M) continue;
#pragma unroll
        for (int j = 0; j < 4; ++j) {
            int n = bn + tx*4 + j;
            if (n >= N) continue;
            float v = acc[i][j];
            if (bias)  v += bias[n];
            if (resid) v += resid[(long)m*ldr + n];
            C[(long)m*ldc + n] = v;
        }
    }
}

// ---------------------------------------------------------------------------
// Depthwise causal (dir=0) / anti-causal (dir=1) conv over time + bias + SiLU.
// Operates on ONE batch chunk: xz is (LL, 2*DIN); xc = cols [0,DIN).
__global__ __launch_bounds__(256) void conv_silu(
    const float* __restrict__ xz, const float* __restrict__ cw,
    const float* __restrict__ cb, float* __restrict__ u, int dir)
{
    long idx = (long)blockIdx.x * 256 + threadIdx.x;
    if (idx >= (long)LL * DIN) return;
    int d  = (int)(idx % DIN);
    int l  = (int)(idx / DIN);
    float acc = cb[d];
#pragma unroll
    for (int k = 0; k < CD; ++k) {
        int j = dir ? (l + 3 - k) : (l - 3 + k);
        if (j >= 0 && j < LL)
            acc += cw[d*CD + k] * xz[(long)j*(2*DIN) + d];
    }
    u[idx] = acc / (1.f + __expf(-acc));   // silu
}

// ---------------------------------------------------------------------------
// Selective scan for ONE batch chunk. Block = 256 thr = 16 channels x 16 states.
// Chunks of 64 timesteps staged into LDS; softplus applied at stage time.
// Fuses: y += D*u ; y *= silu(z) ; writes gated y (may alias u — each block
// stages its rows to LDS before overwriting its own (row,d) elements).
// dpre lives in xz cols [0,DIN); z in xz cols [DIN,2*DIN).
#define TCH 64
__global__ __launch_bounds__(256) void scan_kernel(
    const float* __restrict__ u, const float* __restrict__ xz,
    const float* __restrict__ dbc,
    const float* __restrict__ A_log, const float* __restrict__ Dp,
    float* __restrict__ yg, int dir)
{
    __shared__ float s_u[TCH][16];
    __shared__ float s_dl[TCH][16];
    __shared__ float s_z[TCH][16];
    __shared__ float s_B[TCH][16];
    __shared__ float s_C[TCH][16];
    int tid = threadIdx.x;
    int grp = tid >> 4;          // local d
    int n   = tid & 15;          // state index
    int d0  = blockIdx.x * 16;   // 96 blocks
    int d   = d0 + grp;
    float An = -__expf(A_log[d*NST + n]);
    float Dv = Dp[d];
    float h = 0.f;
    int lc = tid & 15, lr = tid >> 4;
    for (int t0 = 0; t0 < LL; t0 += TCH) {
#pragma unroll
        for (int i = 0; i < 4; ++i) {
            int it = lr + i*16;
            int tau = t0 + it;
            int p = dir ? (LL-1-tau) : tau;
            long row = p;
            s_u[it][lc] = u[row*DIN + d0 + lc];
            float dp = xz[row*(2*DIN) + d0 + lc];
            s_dl[it][lc] = (dp > 20.f) ? dp : log1pf(__expf(dp));
            s_z[it][lc] = xz[row*(2*DIN) + DIN + d0 + lc];
            s_B[it][lc] = dbc[row*(RR+2*NST) + RR + lc];
            s_C[it][lc] = dbc[row*(RR+2*NST) + RR + NST + lc];
        }
        __syncthreads();
#pragma unroll 4
        for (int i = 0; i < TCH; ++i) {
            float delta = s_dl[i][grp];
            float uv    = s_u[i][grp];
            float Bv    = s_B[i][n];
            float Cv    = s_C[i][n];
            float dA = __expf(delta * An);
            h = dA*h + delta*uv*Bv;
            float prod = h*Cv;
#pragma unroll
            for (int off = 8; off >= 1; off >>= 1) prod += __shfl_xor(prod, off);
            if (n == 0) {
                float yv = prod + Dv*uv;
                float z  = s_z[i][grp];
                s_z[i][grp] = yv * z / (1.f + __expf(-z));
            }
        }
        __syncthreads();
#pragma unroll
        for (int i = 0; i < 4; ++i) {
            int it = lr + i*16;
            int tau = t0 + it;
            int p = dir ? (LL-1-tau) : tau;
            yg[(long)p*DIN + d0 + lc] = s_z[it][lc];
        }
        __syncthreads();
    }
}

// ---------------------------------------------------------------------------
extern "C" void kernel_launch(void* const* d_in, const int* in_sizes, int n_in,
                              void* d_out, int out_size, void* d_ws, size_t ws_size,
                              hipStream_t stream)
{
    const float* x        = (const float*)d_in[0];
    const float* in_w     = (const float*)d_in[1];
    const float* conv_w   = (const float*)d_in[2];
    const float* conv_b   = (const float*)d_in[3];
    const float* xproj_w  = (const float*)d_in[4];
    const float* dt_w     = (const float*)d_in[5];
    const float* dt_b     = (const float*)d_in[6];
    const float* A_log    = (const float*)d_in[7];
    const float* Dp       = (const float*)d_in[8];
    const float* out_w    = (const float*)d_in[9];
    const float* ln_g     = (const float*)d_in[10];
    const float* ln_b     = (const float*)d_in[11];
    const float* fus_w    = (const float*)d_in[12];
    const float* fus_b    = (const float*)d_in[13];
    float* out = (float*)d_out;

    // workspace layout (floats), total ~13.5M floats = 54 MB
    float* ws   = (float*)d_ws;
    float* Wc   = ws;                        // 2 * 768*1536 = 2,359,296
    float* xnc  = Wc  + 2L*DD*DIN;           // 2048*768    = 1,572,864
    float* xzc  = xnc + (long)LL*DD;         // 2048*3072   = 6,291,456
    float* uc   = xzc + (long)LL*2*DIN;      // 2048*1536   = 3,145,728
    float* dbcc = uc  + (long)LL*DIN;        // 2048*80     =   163,840

    // Precompute combined output weights:
    // Wc[dir][i,j] = sum_k fus_w[i, dir*768+k] * out_w[dir][k, j]   (768x1536)
    for (int dir = 0; dir < 2; ++dir) {
        gemm_bt<1><<<dim3(24,12), 256, 0, stream>>>(
            fus_w + dir*DD, out_w + (long)dir*DD*DIN, nullptr, nullptr,
            Wc + (long)dir*DD*DIN,
            DD, DIN, DD, 2*DD, DIN, DIN, 0);
    }

    for (int b = 0; b < BB; ++b) {
        const float* xb = x + (long)b*LL*DD;
        float* outb = out + (long)b*LL*DD;
        ln_kernel<<<LL, 256, 0, stream>>>(xb, ln_g, ln_b, xnc);

        for (int dir = 0; dir < 2; ++dir) {
            // xz = xn @ in_w[dir].T      (2048 x 3072, K=768)
            gemm_bt<0><<<dim3(48,32), 256, 0, stream>>>(
                xnc, in_w + (long)dir*2*DIN*DD, nullptr, nullptr, xzc,
                LL, 2*DIN, DD, DD, DD, 2*DIN, 0);
            // u = silu(conv(xc) + cb)
            conv_silu<<<(LL*DIN)/256, 256, 0, stream>>>(
                xzc, conv_w + dir*DIN*CD, conv_b + dir*DIN, uc, dir);
            // dbc = u @ xproj_w[dir].T   (2048 x 80, K=1536)
            gemm_bt<0><<<dim3(2,32), 256, 0, stream>>>(
                uc, xproj_w + (long)dir*(RR+2*NST)*DIN, nullptr, nullptr, dbcc,
                LL, RR+2*NST, DIN, DIN, DIN, RR+2*NST, 0);
            // delta_pre = dt @ dt_w[dir].T + dt_b  -> overwrite xz cols [0,DIN)
            gemm_bt<0><<<dim3(24,32), 256, 0, stream>>>(
                dbcc, dt_w + (long)dir*DIN*RR, dt_b + dir*DIN, nullptr, xzc,
                LL, DIN, RR, RR+2*NST, RR, 2*DIN, 0);
            // selective scan + gating; writes gated y in place over uc
            scan_kernel<<<DIN/16, 256, 0, stream>>>(
                uc, xzc, dbcc, A_log + (long)dir*DIN*NST, Dp + dir*DIN, uc, dir);
            // out rows: dir0: yg@Wc0^T + fus_b + x ; dir1: += yg@Wc1^T
            if (dir == 0) {
                gemm_bt<0><<<dim3(12,32), 256, 0, stream>>>(
                    uc, Wc, fus_b, xb, outb,
                    LL, DD, DIN, DIN, DIN, DD, DD);
            } else {
                gemm_bt<0><<<dim3(12,32), 256, 0, stream>>>(
                    uc, Wc + (long)DD*DIN, nullptr, outb, outb,
                    LL, DD, DIN, DIN, DIN, DD, DD);
            }
        }
    }
}

// Round 3
// 6725.301 us; speedup vs baseline: 1.5897x; 1.5897x over previous
//
#include <hip/hip_runtime.h>
#include <hip/hip_bf16.h>

// Problem constants
#define BB 4
#define LL 2048
#define DD 768
#define DIN 1536
#define NST 16
#define CD 4
#define RR 48
#define TCH 64          // LDS staging sub-tile (timesteps)
#define CH 128          // scan chunk length
#define NCH (LL/CH)     // 16 chunks

// ---------------------------------------------------------------------------
// LayerNorm over last dim (768). One block (256 thr) per row.
__global__ __launch_bounds__(256) void ln_kernel(
    const float* __restrict__ x, const float* __restrict__ g,
    const float* __restrict__ b, float* __restrict__ xn)
{
    int row = blockIdx.x;
    const float* xr = x + (long)row * DD;
    int t = threadIdx.x;
    float v[3];
    float s = 0.f;
#pragma unroll
    for (int i = 0; i < 3; ++i) { v[i] = xr[t + i*256]; s += v[i]; }
#pragma unroll
    for (int off = 32; off >= 1; off >>= 1) s += __shfl_xor(s, off);
    __shared__ float red[4], red2[4];
    int wid = t >> 6;
    if ((t & 63) == 0) red[wid] = s;
    __syncthreads();
    float mean = (red[0]+red[1]+red[2]+red[3]) * (1.f/768.f);
    float vs = 0.f;
#pragma unroll
    for (int i = 0; i < 3; ++i) { float d0 = v[i]-mean; vs += d0*d0; }
#pragma unroll
    for (int off = 32; off >= 1; off >>= 1) vs += __shfl_xor(vs, off);
    if ((t & 63) == 0) red2[wid] = vs;
    __syncthreads();
    float var = (red2[0]+red2[1]+red2[2]+red2[3]) * (1.f/768.f);
    float rstd = rsqrtf(var + 1e-5f);
    float* xo = xn + (long)row * DD;
#pragma unroll
    for (int i = 0; i < 3; ++i) {
        int c = t + i*256;
        xo[c] = (v[i]-mean)*rstd*g[c] + b[c];
    }
}

// ---------------------------------------------------------------------------
// Tiled GEMM: C[m,n] = sum_k A[m,k]*Wacc(n,k) (+bias[n]) (+resid[m,n])
// WMODE=0: Wacc(n,k) = W[n*ldw + k]  (A @ W^T)
// WMODE=1: Wacc(n,k) = W[k*ldw + n]  (A @ W)
template<int WMODE>
__global__ __launch_bounds__(256) void gemm_bt(
    const float* __restrict__ A, const float* __restrict__ W,
    const float* __restrict__ bias, const float* __restrict__ resid,
    float* __restrict__ C,
    int M, int N, int K, int lda, int ldw, int ldc, int ldr)
{
    __shared__ float As[16][65];
    __shared__ float Ws[16][65];
    int bm = blockIdx.y * 64, bn = blockIdx.x * 64;
    int tid = threadIdx.x;
    int lc = tid & 15;
    int lr = tid >> 4;
    int tx = tid & 15, ty = tid >> 4;
    float acc[4][4] = {};
    for (int k0 = 0; k0 < K; k0 += 16) {
        int k = k0 + lc;
        bool kok = (k < K);
#pragma unroll
        for (int i = 0; i < 4; ++i) {
            int m = bm + lr + i*16;
            As[lc][lr + i*16] = (kok && m < M) ? A[(long)m*lda + k] : 0.f;
            int n = bn + lr + i*16;
            float wv = 0.f;
            if (kok && n < N)
                wv = (WMODE == 0) ? W[(long)n*ldw + k] : W[(long)k*ldw + n];
            Ws[lc][lr + i*16] = wv;
        }
        __syncthreads();
#pragma unroll
        for (int kk = 0; kk < 16; ++kk) {
            float a[4], bv[4];
#pragma unroll
            for (int i = 0; i < 4; ++i) a[i]  = As[kk][ty*4+i];
#pragma unroll
            for (int j = 0; j < 4; ++j) bv[j] = Ws[kk][tx*4+j];
#pragma unroll
            for (int i = 0; i < 4; ++i)
#pragma unroll
                for (int j = 0; j < 4; ++j) acc[i][j] += a[i]*bv[j];
        }
        __syncthreads();
    }
#pragma unroll
    for (int i = 0; i < 4; ++i) {
        int m = bm + ty*4 + i;
        if (m >= M) continue;
#pragma unroll
        for (int j = 0; j < 4; ++j) {
            int n = bn + tx*4 + j;
            if (n >= N) continue;
            float v = acc[i][j];
            if (bias)  v += bias[n];
            if (resid) v += resid[(long)m*ldr + n];
            C[(long)m*ldc + n] = v;
        }
    }
}

// ---------------------------------------------------------------------------
// Depthwise causal (dir=0) / anti-causal (dir=1) conv + bias + SiLU.
__global__ __launch_bounds__(256) void conv_silu(
    const float* __restrict__ xz, const float* __restrict__ cw,
    const float* __restrict__ cb, float* __restrict__ u, int dir)
{
    long idx = (long)blockIdx.x * 256 + threadIdx.x;
    if (idx >= (long)LL * DIN) return;
    int d  = (int)(idx % DIN);
    int l  = (int)(idx / DIN);
    float acc = cb[d];
#pragma unroll
    for (int k = 0; k < CD; ++k) {
        int j = dir ? (l + 3 - k) : (l - 3 + k);
        if (j >= 0 && j < LL)
            acc += cw[d*CD + k] * xz[(long)j*(2*DIN) + d];
    }
    u[idx] = acc / (1.f + __expf(-acc));   // silu
}

// ---------------------------------------------------------------------------
// Chunked selective scan, pass 1: per (chunk, d, n) compute transfer pair
//   P = exp(An * sum(delta over chunk)),  S = chunk-local final state (h0=0).
// Block = 256 thr = 16 d x 16 n. Grid = (DIN/16) * NCH.
__global__ __launch_bounds__(256) void scan_pass1(
    const float* __restrict__ u, const float* __restrict__ xz,
    const float* __restrict__ dbc, const float* __restrict__ A_log,
    float* __restrict__ Pc, float* __restrict__ Sc, int dir)
{
    __shared__ float s_u[TCH][16];
    __shared__ float s_dl[TCH][16];
    __shared__ float s_B[TCH][16];
    int tid = threadIdx.x;
    int grp = tid >> 4;
    int n   = tid & 15;
    int d0  = (blockIdx.x % (DIN/16)) * 16;
    int c   = blockIdx.x / (DIN/16);
    int d   = d0 + grp;
    float An = -__expf(A_log[d*NST + n]);
    float h = 0.f, sumd = 0.f;
    int lc = tid & 15, lr = tid >> 4;
    for (int t0 = c*CH; t0 < (c+1)*CH; t0 += TCH) {
#pragma unroll
        for (int i = 0; i < 4; ++i) {
            int it = lr + i*16;
            int tau = t0 + it;
            int p = dir ? (LL-1-tau) : tau;
            s_u[it][lc] = u[(long)p*DIN + d0 + lc];
            float dp = xz[(long)p*(2*DIN) + d0 + lc];
            s_dl[it][lc] = (dp > 20.f) ? dp : log1pf(__expf(dp));
            s_B[it][lc] = dbc[(long)p*(RR+2*NST) + RR + lc];
        }
        __syncthreads();
#pragma unroll 4
        for (int i = 0; i < TCH; ++i) {
            float delta = s_dl[i][grp];
            float uv    = s_u[i][grp];
            float Bv    = s_B[i][n];
            h = __expf(delta * An) * h + delta*uv*Bv;
            sumd += delta;
        }
        __syncthreads();
    }
    long o = ((long)c*DIN + d)*NST + n;
    Pc[o] = __expf(An * sumd);
    Sc[o] = h;
}

// ---------------------------------------------------------------------------
// Chunked scan, mid: exclusive prefix over chunks per (d,n).
// Writes H_in (state at chunk start) IN PLACE over Pc.
__global__ __launch_bounds__(256) void scan_mid(
    float* __restrict__ Pc, const float* __restrict__ Sc)
{
    int idx = blockIdx.x*256 + threadIdx.x;
    if (idx >= DIN*NST) return;
    float h = 0.f;
    for (int c = 0; c < NCH; ++c) {
        long o = (long)c*DIN*NST + idx;
        float p = Pc[o], s = Sc[o];
        Pc[o] = h;              // H_in for chunk c
        h = p*h + s;
    }
}

// ---------------------------------------------------------------------------
// Chunked scan, pass 2: re-run each chunk from H_in; fused y+=D*u, y*=silu(z),
// gated write in place over u (each block stages its own rows first).
__global__ __launch_bounds__(256) void scan_pass2(
    const float* __restrict__ u, const float* __restrict__ xz,
    const float* __restrict__ dbc, const float* __restrict__ Hin,
    const float* __restrict__ A_log, const float* __restrict__ Dp,
    float* __restrict__ yg, int dir)
{
    __shared__ float s_u[TCH][16];
    __shared__ float s_dl[TCH][16];
    __shared__ float s_z[TCH][16];
    __shared__ float s_B[TCH][16];
    __shared__ float s_C[TCH][16];
    int tid = threadIdx.x;
    int grp = tid >> 4;
    int n   = tid & 15;
    int d0  = (blockIdx.x % (DIN/16)) * 16;
    int c   = blockIdx.x / (DIN/16);
    int d   = d0 + grp;
    float An = -__expf(A_log[d*NST + n]);
    float Dv = Dp[d];
    float h = Hin[((long)c*DIN + d)*NST + n];
    int lc = tid & 15, lr = tid >> 4;
    for (int t0 = c*CH; t0 < (c+1)*CH; t0 += TCH) {
#pragma unroll
        for (int i = 0; i < 4; ++i) {
            int it = lr + i*16;
            int tau = t0 + it;
            int p = dir ? (LL-1-tau) : tau;
            s_u[it][lc] = u[(long)p*DIN + d0 + lc];
            float dp = xz[(long)p*(2*DIN) + d0 + lc];
            s_dl[it][lc] = (dp > 20.f) ? dp : log1pf(__expf(dp));
            s_z[it][lc] = xz[(long)p*(2*DIN) + DIN + d0 + lc];
            s_B[it][lc] = dbc[(long)p*(RR+2*NST) + RR + lc];
            s_C[it][lc] = dbc[(long)p*(RR+2*NST) + RR + NST + lc];
        }
        __syncthreads();
#pragma unroll 4
        for (int i = 0; i < TCH; ++i) {
            float delta = s_dl[i][grp];
            float uv    = s_u[i][grp];
            float Bv    = s_B[i][n];
            float Cv    = s_C[i][n];
            h = __expf(delta * An) * h + delta*uv*Bv;
            float prod = h*Cv;
#pragma unroll
            for (int off = 8; off >= 1; off >>= 1) prod += __shfl_xor(prod, off);
            if (n == 0) {
                float yv = prod + Dv*uv;
                float z  = s_z[i][grp];
                s_z[i][grp] = yv * z / (1.f + __expf(-z));
            }
        }
        __syncthreads();
#pragma unroll
        for (int i = 0; i < 4; ++i) {
            int it = lr + i*16;
            int tau = t0 + it;
            int p = dir ? (LL-1-tau) : tau;
            yg[(long)p*DIN + d0 + lc] = s_z[it][lc];
        }
        __syncthreads();
    }
}

// ---------------------------------------------------------------------------
extern "C" void kernel_launch(void* const* d_in, const int* in_sizes, int n_in,
                              void* d_out, int out_size, void* d_ws, size_t ws_size,
                              hipStream_t stream)
{
    const float* x        = (const float*)d_in[0];
    const float* in_w     = (const float*)d_in[1];
    const float* conv_w   = (const float*)d_in[2];
    const float* conv_b   = (const float*)d_in[3];
    const float* xproj_w  = (const float*)d_in[4];
    const float* dt_w     = (const float*)d_in[5];
    const float* dt_b     = (const float*)d_in[6];
    const float* A_log    = (const float*)d_in[7];
    const float* Dp       = (const float*)d_in[8];
    const float* out_w    = (const float*)d_in[9];
    const float* ln_g     = (const float*)d_in[10];
    const float* ln_b     = (const float*)d_in[11];
    const float* fus_w    = (const float*)d_in[12];
    const float* fus_b    = (const float*)d_in[13];
    float* out = (float*)d_out;

    // workspace layout (floats), total ~14.3M floats = ~57 MB
    float* ws   = (float*)d_ws;
    float* Wc   = ws;                        // 2 * 768*1536 = 2,359,296
    float* xnc  = Wc  + 2L*DD*DIN;           // 2048*768    = 1,572,864
    float* xzc  = xnc + (long)LL*DD;         // 2048*3072   = 6,291,456
    float* uc   = xzc + (long)LL*2*DIN;      // 2048*1536   = 3,145,728
    float* dbcc = uc  + (long)LL*DIN;        // 2048*80     =   163,840
    float* Pc   = dbcc+ (long)LL*(RR+2*NST); // 16*1536*16  =   393,216
    float* Sc   = Pc  + (long)NCH*DIN*NST;   // 16*1536*16  =   393,216

    // Precompute combined output weights:
    // Wc[dir][i,j] = sum_k fus_w[i, dir*768+k] * out_w[dir][k, j]   (768x1536)
    for (int dir = 0; dir < 2; ++dir) {
        gemm_bt<1><<<dim3(24,12), 256, 0, stream>>>(
            fus_w + dir*DD, out_w + (long)dir*DD*DIN, nullptr, nullptr,
            Wc + (long)dir*DD*DIN,
            DD, DIN, DD, 2*DD, DIN, DIN, 0);
    }

    for (int b = 0; b < BB; ++b) {
        const float* xb = x + (long)b*LL*DD;
        float* outb = out + (long)b*LL*DD;
        ln_kernel<<<LL, 256, 0, stream>>>(xb, ln_g, ln_b, xnc);

        for (int dir = 0; dir < 2; ++dir) {
            // xz = xn @ in_w[dir].T      (2048 x 3072, K=768)
            gemm_bt<0><<<dim3(48,32), 256, 0, stream>>>(
                xnc, in_w + (long)dir*2*DIN*DD, nullptr, nullptr, xzc,
                LL, 2*DIN, DD, DD, DD, 2*DIN, 0);
            // u = silu(conv(xc) + cb)
            conv_silu<<<(LL*DIN)/256, 256, 0, stream>>>(
                xzc, conv_w + dir*DIN*CD, conv_b + dir*DIN, uc, dir);
            // dbc = u @ xproj_w[dir].T   (2048 x 80, K=1536)
            gemm_bt<0><<<dim3(2,32), 256, 0, stream>>>(
                uc, xproj_w + (long)dir*(RR+2*NST)*DIN, nullptr, nullptr, dbcc,
                LL, RR+2*NST, DIN, DIN, DIN, RR+2*NST, 0);
            // delta_pre = dt @ dt_w[dir].T + dt_b  -> overwrite xz cols [0,DIN)
            gemm_bt<0><<<dim3(24,32), 256, 0, stream>>>(
                dbcc, dt_w + (long)dir*DIN*RR, dt_b + dir*DIN, nullptr, xzc,
                LL, DIN, RR, RR+2*NST, RR, 2*DIN, 0);
            // chunked selective scan (time-parallel): pass1 -> mid -> pass2
            scan_pass1<<<(DIN/16)*NCH, 256, 0, stream>>>(
                uc, xzc, dbcc, A_log + (long)dir*DIN*NST, Pc, Sc, dir);
            scan_mid<<<(DIN*NST)/256, 256, 0, stream>>>(Pc, Sc);
            scan_pass2<<<(DIN/16)*NCH, 256, 0, stream>>>(
                uc, xzc, dbcc, Pc, A_log + (long)dir*DIN*NST, Dp + dir*DIN,
                uc, dir);
            // out rows: dir0: yg@Wc0^T + fus_b + x ; dir1: += yg@Wc1^T
            if (dir == 0) {
                gemm_bt<0><<<dim3(12,32), 256, 0, stream>>>(
                    uc, Wc, fus_b, xb, outb,
                    LL, DD, DIN, DIN, DIN, DD, DD);
            } else {
                gemm_bt<0><<<dim3(12,32), 256, 0, stream>>>(
                    uc, Wc + (long)DD*DIN, nullptr, outb, outb,
                    LL, DD, DIN, DIN, DIN, DD, DD);
            }
        }
    }
}

// Round 4
// 3630.994 us; speedup vs baseline: 2.9444x; 1.8522x over previous
//
#include <hip/hip_runtime.h>
#include <hip/hip_bf16.h>

// Problem constants
#define BB 4
#define LL 2048
#define DD 768
#define DIN 1536
#define NST 16
#define CD 4
#define RR 48
#define TCH 64          // LDS staging sub-tile (timesteps)
#define CH 128          // scan chunk length
#define NCH (LL/CH)     // 16 chunks
#define NBC 32          // B,C columns (2*NST)
#define NCOMB (DIN+NBC) // 1568: combined [delta | B | C] GEMM width

typedef unsigned short ushort_t;
typedef __attribute__((ext_vector_type(4))) float f32x4;
typedef __attribute__((ext_vector_type(8))) short bf16x8;

static __device__ __forceinline__ ushort_t f2bf(float f) {
    unsigned int u = __float_as_uint(f);
    u += 0x7FFF + ((u >> 16) & 1);          // RNE
    return (ushort_t)(u >> 16);
}

// ---------------------------------------------------------------------------
// LayerNorm over last dim (768). One block (256 thr) per row.
__global__ __launch_bounds__(256) void ln_kernel(
    const float* __restrict__ x, const float* __restrict__ g,
    const float* __restrict__ b, float* __restrict__ xn)
{
    int row = blockIdx.x;
    const float* xr = x + (long)row * DD;
    int t = threadIdx.x;
    float v[3];
    float s = 0.f;
#pragma unroll
    for (int i = 0; i < 3; ++i) { v[i] = xr[t + i*256]; s += v[i]; }
#pragma unroll
    for (int off = 32; off >= 1; off >>= 1) s += __shfl_xor(s, off);
    __shared__ float red[4], red2[4];
    int wid = t >> 6;
    if ((t & 63) == 0) red[wid] = s;
    __syncthreads();
    float mean = (red[0]+red[1]+red[2]+red[3]) * (1.f/768.f);
    float vs = 0.f;
#pragma unroll
    for (int i = 0; i < 3; ++i) { float d0 = v[i]-mean; vs += d0*d0; }
#pragma unroll
    for (int off = 32; off >= 1; off >>= 1) vs += __shfl_xor(vs, off);
    if ((t & 63) == 0) red2[wid] = vs;
    __syncthreads();
    float var = (red2[0]+red2[1]+red2[2]+red2[3]) * (1.f/768.f);
    float rstd = rsqrtf(var + 1e-5f);
    float* xo = xn + (long)row * DD;
#pragma unroll
    for (int i = 0; i < 3; ++i) {
        int c = t + i*256;
        xo[c] = (v[i]-mean)*rstd*g[c] + b[c];
    }
}

// ---------------------------------------------------------------------------
// f32 tiled GEMM, A @ W (WMODE=1 only kept, for Wc precompute).
template<int WMODE>
__global__ __launch_bounds__(256) void gemm_bt(
    const float* __restrict__ A, const float* __restrict__ W,
    float* __restrict__ C, int M, int N, int K, int lda, int ldw, int ldc)
{
    __shared__ float As[16][65];
    __shared__ float Ws[16][65];
    int bm = blockIdx.y * 64, bn = blockIdx.x * 64;
    int tid = threadIdx.x;
    int lc = tid & 15;
    int lr = tid >> 4;
    int tx = tid & 15, ty = tid >> 4;
    float acc[4][4] = {};
    for (int k0 = 0; k0 < K; k0 += 16) {
        int k = k0 + lc;
        bool kok = (k < K);
#pragma unroll
        for (int i = 0; i < 4; ++i) {
            int m = bm + lr + i*16;
            As[lc][lr + i*16] = (kok && m < M) ? A[(long)m*lda + k] : 0.f;
            int n = bn + lr + i*16;
            float wv = 0.f;
            if (kok && n < N)
                wv = (WMODE == 0) ? W[(long)n*ldw + k] : W[(long)k*ldw + n];
            Ws[lc][lr + i*16] = wv;
        }
        __syncthreads();
#pragma unroll
        for (int kk = 0; kk < 16; ++kk) {
            float a[4], bv[4];
#pragma unroll
            for (int i = 0; i < 4; ++i) a[i]  = As[kk][ty*4+i];
#pragma unroll
            for (int j = 0; j < 4; ++j) bv[j] = Ws[kk][tx*4+j];
#pragma unroll
            for (int i = 0; i < 4; ++i)
#pragma unroll
                for (int j = 0; j < 4; ++j) acc[i][j] += a[i]*bv[j];
        }
        __syncthreads();
    }
#pragma unroll
    for (int i = 0; i < 4; ++i) {
        int m = bm + ty*4 + i;
        if (m >= M) continue;
#pragma unroll
        for (int j = 0; j < 4; ++j) {
            int n = bn + tx*4 + j;
            if (n >= N) continue;
            C[(long)m*ldc + n] = acc[i][j];
        }
    }
}

// ---------------------------------------------------------------------------
// elementwise f32 -> bf16 convert
__global__ __launch_bounds__(256) void cvt_bf16(
    const float* __restrict__ in, ushort_t* __restrict__ out, long n)
{
    long i = (long)blockIdx.x*256 + threadIdx.x;
    if (i < n) out[i] = f2bf(in[i]);
}

// ---------------------------------------------------------------------------
// Build combined [Wdc | xw_B | xw_C] bf16 weight (NCOMB x DIN):
//   row d<DIN:  Wdc[d,k] = sum_r dt_w[d,r] * xw[r,k]
//   row d>=DIN: xw[RR + (d-DIN), k]
__global__ __launch_bounds__(256) void wdcat_build(
    const float* __restrict__ dt_w, const float* __restrict__ xw,
    ushort_t* __restrict__ out)
{
    long idx = (long)blockIdx.x*256 + threadIdx.x;
    if (idx >= (long)NCOMB*DIN) return;
    int k = (int)(idx % DIN);
    int d = (int)(idx / DIN);
    float acc;
    if (d < DIN) {
        acc = 0.f;
#pragma unroll 8
        for (int r = 0; r < RR; ++r)
            acc += dt_w[d*RR + r] * xw[(long)r*DIN + k];
    } else {
        acc = xw[(long)(RR + d - DIN)*DIN + k];
    }
    out[idx] = f2bf(acc);
}

// ---------------------------------------------------------------------------
// MFMA GEMM: C[m,n] = sum_k A_f32[m,k] * Wbf[n,k]  (+bias[n]) (+resid[m,n])
// A reg-staged f32->bf16 into LDS. Wbf is bf16 row-major [N][K].
// 128x128 tile, BK=32, 256 thr = 4 waves (2x2 of 64x64), 16x16x32 MFMA.
// Requires: M%128==0, K%32==0, lda/ldw arbitrary (row-major, = K for W).
// Split epilogue: cols n<n_split -> C (ldc, +bias,+resid); n>=n_split -> C2 (ldc2).
__global__ __launch_bounds__(256) void gemm_mfma(
    const float* __restrict__ A, const ushort_t* __restrict__ Wb,
    const float* __restrict__ bias, const float* __restrict__ resid,
    float* __restrict__ C, float* __restrict__ C2,
    int M, int N, int K, int lda, int ldc, int ldr, int n_split, int ldc2)
{
    __shared__ __attribute__((aligned(16))) ushort_t As[128][40];
    __shared__ __attribute__((aligned(16))) ushort_t Bs[128][40];
    int tid = threadIdx.x;
    int bm = blockIdx.y * 128, bn = blockIdx.x * 128;
    int lane = tid & 63, w = tid >> 6;
    int wr = w >> 1, wc = w & 1;
    int lrow = lane & 15, kg = lane >> 4;

    f32x4 acc[4][4] = {};

    for (int k0 = 0; k0 < K; k0 += 32) {
        __syncthreads();   // previous iter's LDS reads done
        // stage A: 128 rows x 32 k (f32 -> bf16). 1024 float4 chunks / 256 thr.
#pragma unroll
        for (int i = 0; i < 4; ++i) {
            int ci = (i << 8) + tid;
            int row = ci >> 3;          // 0..127
            int ch  = ci & 7;           // 0..7 (4 floats each)
            const float4 v = *(const float4*)&A[(long)(bm+row)*lda + k0 + ch*4];
            ushort4 o;
            o.x = f2bf(v.x); o.y = f2bf(v.y); o.z = f2bf(v.z); o.w = f2bf(v.w);
            *(ushort4*)&As[row][ch*4] = o;
        }
        // stage B: 128 rows x 32 k bf16 direct. 512 16B chunks / 256 thr.
#pragma unroll
        for (int i = 0; i < 2; ++i) {
            int ci = (i << 8) + tid;
            int row = ci >> 2;          // 0..127
            int ch  = ci & 3;           // 0..3 (8 bf16 each)
            bf16x8 wv = {};
            if (bn + row < N)
                wv = *(const bf16x8*)&Wb[(long)(bn+row)*K + k0 + ch*8];
            *(bf16x8*)&Bs[row][ch*8] = wv;
        }
        __syncthreads();
        // compute: each wave 4x4 frags of 16x16, one K=32 step
        bf16x8 af[4], bfv[4];
#pragma unroll
        for (int mi = 0; mi < 4; ++mi)
            af[mi] = *(const bf16x8*)&As[wr*64 + mi*16 + lrow][kg*8];
#pragma unroll
        for (int ni = 0; ni < 4; ++ni)
            bfv[ni] = *(const bf16x8*)&Bs[wc*64 + ni*16 + lrow][kg*8];
#pragma unroll
        for (int mi = 0; mi < 4; ++mi)
#pragma unroll
            for (int ni = 0; ni < 4; ++ni)
                acc[mi][ni] = __builtin_amdgcn_mfma_f32_16x16x32_bf16(
                    af[mi], bfv[ni], acc[mi][ni], 0, 0, 0);
    }

    // epilogue: C/D frag mapping col=lane&15, row=(lane>>4)*4+reg
#pragma unroll
    for (int mi = 0; mi < 4; ++mi) {
#pragma unroll
        for (int ni = 0; ni < 4; ++ni) {
            int n = bn + wc*64 + ni*16 + lrow;
            if (n >= N) continue;
#pragma unroll
            for (int reg = 0; reg < 4; ++reg) {
                int m = bm + wr*64 + mi*16 + kg*4 + reg;
                float v = acc[mi][ni][reg];
                if (n < n_split) {
                    if (bias)  v += bias[n];
                    if (resid) v += resid[(long)m*ldr + n];
                    C[(long)m*ldc + n] = v;
                } else {
                    C2[(long)m*ldc2 + (n - n_split)] = v;
                }
            }
        }
    }
}

// ---------------------------------------------------------------------------
// Depthwise causal (dir=0) / anti-causal (dir=1) conv + bias + SiLU.
__global__ __launch_bounds__(256) void conv_silu(
    const float* __restrict__ xz, const float* __restrict__ cw,
    const float* __restrict__ cb, float* __restrict__ u, int dir)
{
    long idx = (long)blockIdx.x * 256 + threadIdx.x;
    if (idx >= (long)LL * DIN) return;
    int d  = (int)(idx % DIN);
    int l  = (int)(idx / DIN);
    float acc = cb[d];
#pragma unroll
    for (int k = 0; k < CD; ++k) {
        int j = dir ? (l + 3 - k) : (l - 3 + k);
        if (j >= 0 && j < LL)
            acc += cw[d*CD + k] * xz[(long)j*(2*DIN) + d];
    }
    u[idx] = acc / (1.f + __expf(-acc));   // silu
}

// ---------------------------------------------------------------------------
// Chunked selective scan, pass 1: per (chunk, d, n) compute transfer pair
//   P = exp(An * sum(delta over chunk)),  S = chunk-local final state (h0=0).
__global__ __launch_bounds__(256) void scan_pass1(
    const float* __restrict__ u, const float* __restrict__ xz,
    const float* __restrict__ bc, const float* __restrict__ A_log,
    float* __restrict__ Pc, float* __restrict__ Sc, int dir)
{
    __shared__ float s_u[TCH][16];
    __shared__ float s_dl[TCH][16];
    __shared__ float s_B[TCH][16];
    int tid = threadIdx.x;
    int grp = tid >> 4;
    int n   = tid & 15;
    int d0  = (blockIdx.x % (DIN/16)) * 16;
    int c   = blockIdx.x / (DIN/16);
    int d   = d0 + grp;
    float An = -__expf(A_log[d*NST + n]);
    float h = 0.f, sumd = 0.f;
    int lc = tid & 15, lr = tid >> 4;
    for (int t0 = c*CH; t0 < (c+1)*CH; t0 += TCH) {
#pragma unroll
        for (int i = 0; i < 4; ++i) {
            int it = lr + i*16;
            int tau = t0 + it;
            int p = dir ? (LL-1-tau) : tau;
            s_u[it][lc] = u[(long)p*DIN + d0 + lc];
            float dp = xz[(long)p*(2*DIN) + d0 + lc];
            s_dl[it][lc] = (dp > 20.f) ? dp : log1pf(__expf(dp));
            s_B[it][lc] = bc[(long)p*NBC + lc];
        }
        __syncthreads();
#pragma unroll 4
        for (int i = 0; i < TCH; ++i) {
            float delta = s_dl[i][grp];
            float uv    = s_u[i][grp];
            float Bv    = s_B[i][n];
            h = __expf(delta * An) * h + delta*uv*Bv;
            sumd += delta;
        }
        __syncthreads();
    }
    long o = ((long)c*DIN + d)*NST + n;
    Pc[o] = __expf(An * sumd);
    Sc[o] = h;
}

// ---------------------------------------------------------------------------
// Chunked scan, mid: exclusive prefix over chunks per (d,n); Hin in place.
__global__ __launch_bounds__(256) void scan_mid(
    float* __restrict__ Pc, const float* __restrict__ Sc)
{
    int idx = blockIdx.x*256 + threadIdx.x;
    if (idx >= DIN*NST) return;
    float h = 0.f;
    for (int c = 0; c < NCH; ++c) {
        long o = (long)c*DIN*NST + idx;
        float p = Pc[o], s = Sc[o];
        Pc[o] = h;
        h = p*h + s;
    }
}

// ---------------------------------------------------------------------------
// Chunked scan, pass 2: re-run chunk from Hin; fused y+=D*u, y*=silu(z),
// gated write in place over u.
__global__ __launch_bounds__(256) void scan_pass2(
    const float* __restrict__ u, const float* __restrict__ xz,
    const float* __restrict__ bc, const float* __restrict__ Hin,
    const float* __restrict__ A_log, const float* __restrict__ Dp,
    float* __restrict__ yg, int dir)
{
    __shared__ float s_u[TCH][16];
    __shared__ float s_dl[TCH][16];
    __shared__ float s_z[TCH][16];
    __shared__ float s_B[TCH][16];
    __shared__ float s_C[TCH][16];
    int tid = threadIdx.x;
    int grp = tid >> 4;
    int n   = tid & 15;
    int d0  = (blockIdx.x % (DIN/16)) * 16;
    int c   = blockIdx.x / (DIN/16);
    int d   = d0 + grp;
    float An = -__expf(A_log[d*NST + n]);
    float Dv = Dp[d];
    float h = Hin[((long)c*DIN + d)*NST + n];
    int lc = tid & 15, lr = tid >> 4;
    for (int t0 = c*CH; t0 < (c+1)*CH; t0 += TCH) {
#pragma unroll
        for (int i = 0; i < 4; ++i) {
            int it = lr + i*16;
            int tau = t0 + it;
            int p = dir ? (LL-1-tau) : tau;
            s_u[it][lc] = u[(long)p*DIN + d0 + lc];
            float dp = xz[(long)p*(2*DIN) + d0 + lc];
            s_dl[it][lc] = (dp > 20.f) ? dp : log1pf(__expf(dp));
            s_z[it][lc] = xz[(long)p*(2*DIN) + DIN + d0 + lc];
            s_B[it][lc] = bc[(long)p*NBC + lc];
            s_C[it][lc] = bc[(long)p*NBC + NST + lc];
        }
        __syncthreads();
#pragma unroll 4
        for (int i = 0; i < TCH; ++i) {
            float delta = s_dl[i][grp];
            float uv    = s_u[i][grp];
            float Bv    = s_B[i][n];
            float Cv    = s_C[i][n];
            h = __expf(delta * An) * h + delta*uv*Bv;
            float prod = h*Cv;
#pragma unroll
            for (int off = 8; off >= 1; off >>= 1) prod += __shfl_xor(prod, off);
            if (n == 0) {
                float yv = prod + Dv*uv;
                float z  = s_z[i][grp];
                s_z[i][grp] = yv * z / (1.f + __expf(-z));
            }
        }
        __syncthreads();
#pragma unroll
        for (int i = 0; i < 4; ++i) {
            int it = lr + i*16;
            int tau = t0 + it;
            int p = dir ? (LL-1-tau) : tau;
            yg[(long)p*DIN + d0 + lc] = s_z[it][lc];
        }
        __syncthreads();
    }
}

// ---------------------------------------------------------------------------
extern "C" void kernel_launch(void* const* d_in, const int* in_sizes, int n_in,
                              void* d_out, int out_size, void* d_ws, size_t ws_size,
                              hipStream_t stream)
{
    const float* x        = (const float*)d_in[0];
    const float* in_w     = (const float*)d_in[1];
    const float* conv_w   = (const float*)d_in[2];
    const float* conv_b   = (const float*)d_in[3];
    const float* xproj_w  = (const float*)d_in[4];
    const float* dt_w     = (const float*)d_in[5];
    const float* dt_b     = (const float*)d_in[6];
    const float* A_log    = (const float*)d_in[7];
    const float* Dp       = (const float*)d_in[8];
    const float* out_w    = (const float*)d_in[9];
    const float* ln_g     = (const float*)d_in[10];
    const float* ln_b     = (const float*)d_in[11];
    const float* fus_w    = (const float*)d_in[12];
    const float* fus_b    = (const float*)d_in[13];
    float* out = (float*)d_out;

    // workspace layout, ~71 MB total
    float* ws   = (float*)d_ws;
    float* xnc  = ws;                        // 2048*768    = 1,572,864 f32
    float* xzc  = xnc + (long)LL*DD;         // 2048*3072   = 6,291,456
    float* uc   = xzc + (long)LL*2*DIN;      // 2048*1536   = 3,145,728
    float* bcb  = uc  + (long)LL*DIN;        // 2048*32     =    65,536
    float* Pc   = bcb + (long)LL*NBC;        // 16*1536*16  =   393,216
    float* Sc   = Pc  + (long)NCH*DIN*NST;   // 16*1536*16  =   393,216
    ushort_t* in_w_bf = (ushort_t*)(Sc + (long)NCH*DIN*NST); // 2*3072*768
    ushort_t* wdc_bf  = in_w_bf + 2L*2*DIN*DD;               // 2*1568*1536
    ushort_t* wc_bf   = wdc_bf  + 2L*NCOMB*DIN;              // 2*768*1536

    // ---- weight prep (per call, batch-independent) ----
    for (int dir = 0; dir < 2; ++dir) {
        // in_proj weights -> bf16
        cvt_bf16<<<(2*DIN*DD)/256, 256, 0, stream>>>(
            in_w + (long)dir*2*DIN*DD, in_w_bf + (long)dir*2*DIN*DD,
            (long)2*DIN*DD);
        // combined [dt-fold | B | C] weights -> bf16
        wdcat_build<<<(NCOMB*DIN)/256, 256, 0, stream>>>(
            dt_w + (long)dir*DIN*RR, xproj_w + (long)dir*(RR+2*NST)*DIN,
            wdc_bf + (long)dir*NCOMB*DIN);
        // Wc[dir][i,j] = sum_k fus_w[i, dir*768+k]*out_w[dir][k,j] -> f32 scratch -> bf16
        gemm_bt<1><<<dim3(24,12), 256, 0, stream>>>(
            fus_w + dir*DD, out_w + (long)dir*DD*DIN, xzc,
            DD, DIN, DD, 2*DD, DIN, DIN);
        cvt_bf16<<<(DD*DIN)/256, 256, 0, stream>>>(
            xzc, wc_bf + (long)dir*DD*DIN, (long)DD*DIN);
    }

    for (int b = 0; b < BB; ++b) {
        const float* xb = x + (long)b*LL*DD;
        float* outb = out + (long)b*LL*DD;
        ln_kernel<<<LL, 256, 0, stream>>>(xb, ln_g, ln_b, xnc);

        for (int dir = 0; dir < 2; ++dir) {
            // xz = xn @ in_w[dir].T   (2048 x 3072, K=768)
            gemm_mfma<<<dim3(24,16), 256, 0, stream>>>(
                xnc, in_w_bf + (long)dir*2*DIN*DD, nullptr, nullptr,
                xzc, nullptr, LL, 2*DIN, DD, DD, 2*DIN, 0, 2*DIN, 0);
            // u = silu(conv(xc) + cb)
            conv_silu<<<(LL*DIN)/256, 256, 0, stream>>>(
                xzc, conv_w + dir*DIN*CD, conv_b + dir*DIN, uc, dir);
            // [delta_pre | B | C] = u @ Wcomb.T  (2048 x 1568, K=1536)
            // delta_pre (+dt_b) -> xz cols [0,DIN); B,C -> bcb
            gemm_mfma<<<dim3(13,16), 256, 0, stream>>>(
                uc, wdc_bf + (long)dir*NCOMB*DIN, dt_b + dir*DIN, nullptr,
                xzc, bcb, LL, NCOMB, DIN, DIN, 2*DIN, 0, DIN, NBC);
            // chunked selective scan: pass1 -> mid -> pass2
            scan_pass1<<<(DIN/16)*NCH, 256, 0, stream>>>(
                uc, xzc, bcb, A_log + (long)dir*DIN*NST, Pc, Sc, dir);
            scan_mid<<<(DIN*NST)/256, 256, 0, stream>>>(Pc, Sc);
            scan_pass2<<<(DIN/16)*NCH, 256, 0, stream>>>(
                uc, xzc, bcb, Pc, A_log + (long)dir*DIN*NST, Dp + dir*DIN,
                uc, dir);
            // out: dir0: yg@Wc0^T + fus_b + x ; dir1: += yg@Wc1^T
            if (dir == 0) {
                gemm_mfma<<<dim3(6,16), 256, 0, stream>>>(
                    uc, wc_bf, fus_b, xb,
                    outb, nullptr, LL, DD, DIN, DIN, DD, DD, DD, 0);
            } else {
                gemm_mfma<<<dim3(6,16), 256, 0, stream>>>(
                    uc, wc_bf + (long)DD*DIN, nullptr, outb,
                    outb, nullptr, LL, DD, DIN, DIN, DD, DD, DD, 0);
            }
        }
    }
}

// Round 5
// 2149.893 us; speedup vs baseline: 4.9729x; 1.6889x over previous
//
#include <hip/hip_runtime.h>
#include <hip/hip_bf16.h>

// Problem constants
#define BB 4
#define LL 2048
#define DD 768
#define DIN 1536
#define NST 16
#define CD 4
#define RR 48
#define TCH 64          // LDS staging sub-tile (timesteps)
#define CH 128          // scan chunk length
#define NCH (LL/CH)     // 16 chunks
#define NBC 32          // B,C columns (2*NST)
#define NCOMB (DIN+NBC) // 1568: combined [delta | B | C] GEMM width

typedef unsigned short ushort_t;
typedef unsigned int u32;
typedef __attribute__((ext_vector_type(4))) float f32x4;
typedef __attribute__((ext_vector_type(8))) short bf16x8;

static __device__ __forceinline__ ushort_t f2bf(float f) {
    unsigned int u = __float_as_uint(f);
    u += 0x7FFF + ((u >> 16) & 1);          // RNE
    return (ushort_t)(u >> 16);
}

static __device__ __forceinline__ void gload_lds16(const void* g, void* l) {
    __builtin_amdgcn_global_load_lds(
        (const __attribute__((address_space(1))) u32*)g,
        (__attribute__((address_space(3))) u32*)l, 16, 0, 0);
}

// ---------------------------------------------------------------------------
// LayerNorm over last dim (768). One block (256 thr) per row. bf16 output.
__global__ __launch_bounds__(256) void ln_kernel(
    const float* __restrict__ x, const float* __restrict__ g,
    const float* __restrict__ b, ushort_t* __restrict__ xn)
{
    int row = blockIdx.x;
    const float* xr = x + (long)row * DD;
    int t = threadIdx.x;
    float v[3];
    float s = 0.f;
#pragma unroll
    for (int i = 0; i < 3; ++i) { v[i] = xr[t + i*256]; s += v[i]; }
#pragma unroll
    for (int off = 32; off >= 1; off >>= 1) s += __shfl_xor(s, off);
    __shared__ float red[4], red2[4];
    int wid = t >> 6;
    if ((t & 63) == 0) red[wid] = s;
    __syncthreads();
    float mean = (red[0]+red[1]+red[2]+red[3]) * (1.f/768.f);
    float vs = 0.f;
#pragma unroll
    for (int i = 0; i < 3; ++i) { float d0 = v[i]-mean; vs += d0*d0; }
#pragma unroll
    for (int off = 32; off >= 1; off >>= 1) vs += __shfl_xor(vs, off);
    if ((t & 63) == 0) red2[wid] = vs;
    __syncthreads();
    float var = (red2[0]+red2[1]+red2[2]+red2[3]) * (1.f/768.f);
    float rstd = rsqrtf(var + 1e-5f);
    ushort_t* xo = xn + (long)row * DD;
#pragma unroll
    for (int i = 0; i < 3; ++i) {
        int c = t + i*256;
        xo[c] = f2bf((v[i]-mean)*rstd*g[c] + b[c]);
    }
}

// ---------------------------------------------------------------------------
// elementwise f32 -> bf16 convert
__global__ __launch_bounds__(256) void cvt_bf16(
    const float* __restrict__ in, ushort_t* __restrict__ out, long n)
{
    long i = (long)blockIdx.x*256 + threadIdx.x;
    if (i < n) out[i] = f2bf(in[i]);
}

// ---------------------------------------------------------------------------
// transpose-convert out_w (DD x DIN, row-major) -> owt (DIN x DD) bf16
__global__ __launch_bounds__(256) void owt_cvt(
    const float* __restrict__ ow, ushort_t* __restrict__ out)
{
    long idx = (long)blockIdx.x*256 + threadIdx.x;
    if (idx >= (long)DIN*DD) return;
    int k = (int)(idx % DD);   // source row
    int n = (int)(idx / DD);   // source col
    out[idx] = f2bf(ow[(long)k*DIN + n]);
}

// ---------------------------------------------------------------------------
// Build combined [Wdc | xw_B | xw_C] bf16 weight (NCOMB x DIN):
//   row d<DIN:  Wdc[d,k] = sum_r dt_w[d,r] * xw[r,k]
//   row d>=DIN: xw[RR + (d-DIN), k]
__global__ __launch_bounds__(256) void wdcat_build(
    const float* __restrict__ dt_w, const float* __restrict__ xw,
    ushort_t* __restrict__ out)
{
    long idx = (long)blockIdx.x*256 + threadIdx.x;
    if (idx >= (long)NCOMB*DIN) return;
    int k = (int)(idx % DIN);
    int d = (int)(idx / DIN);
    float acc;
    if (d < DIN) {
        acc = 0.f;
#pragma unroll 8
        for (int r = 0; r < RR; ++r)
            acc += dt_w[d*RR + r] * xw[(long)r*DIN + k];
    } else {
        acc = xw[(long)(RR + d - DIN)*DIN + k];
    }
    out[idx] = f2bf(acc);
}

// ---------------------------------------------------------------------------
// MFMA GEMM, bf16 x bf16 -> f32: C[m,n] = sum_k A[m,k]*Wb[n,k] (+bias)(+resid)
// Both operands staged via global_load_lds (16B, linear LDS layout).
// 128x128 tile, BK=32, 256 thr = 4 waves (2x2 of 64x64), 16x16x32 MFMA.
// Requires M%128==0, K%32==0. B rows clamped to N-1 (cols >=N discarded).
// Split epilogue: n<n_split -> C (+bias,+resid); n>=n_split -> C2.
__global__ __launch_bounds__(256) void gemm_mfma(
    const ushort_t* __restrict__ A, const ushort_t* __restrict__ Wb,
    const float* __restrict__ bias, const float* __restrict__ resid,
    float* __restrict__ C, float* __restrict__ C2,
    int M, int N, int K, int lda, int ldc, int ldr, int n_split, int ldc2)
{
    __shared__ __attribute__((aligned(16))) ushort_t As[128*32];
    __shared__ __attribute__((aligned(16))) ushort_t Bs[128*32];
    int tid = threadIdx.x;
    int bm = blockIdx.y * 128, bn = blockIdx.x * 128;
    int lane = tid & 63, w = tid >> 6;
    int wr = w >> 1, wc = w & 1;
    int lrow = lane & 15, kg = lane >> 4;
    // staging geometry: chunk = 1024B = 16 rows x 4 slots of 16B
    int srowA = lane >> 2;          // 0..15 within chunk
    int sc8  = lane & 3;            // 16B slot within 64B row

    f32x4 acc[4][4] = {};

    for (int k0 = 0; k0 < K; k0 += 32) {
        __syncthreads();   // prior reads done; also drains prior vm
#pragma unroll
        for (int it = 0; it < 2; ++it) {
            int chunk = it*4 + w;                  // 0..7
            int row = chunk*16 + srowA;            // 0..127
            gload_lds16(&A[(long)(bm+row)*lda + k0 + sc8*8], &As[chunk*512]);
        }
#pragma unroll
        for (int it = 0; it < 2; ++it) {
            int chunk = it*4 + w;
            int row = chunk*16 + srowA;
            int n = bn + row; if (n > N-1) n = N-1;
            gload_lds16(&Wb[(long)n*K + k0 + sc8*8], &Bs[chunk*512]);
        }
        __syncthreads();   // compiler emits vmcnt(0) drain before barrier
        bf16x8 af[4], bfv[4];
#pragma unroll
        for (int mi = 0; mi < 4; ++mi)
            af[mi] = *(const bf16x8*)&As[(wr*64 + mi*16 + lrow)*32 + kg*8];
#pragma unroll
        for (int ni = 0; ni < 4; ++ni)
            bfv[ni] = *(const bf16x8*)&Bs[(wc*64 + ni*16 + lrow)*32 + kg*8];
#pragma unroll
        for (int mi = 0; mi < 4; ++mi)
#pragma unroll
            for (int ni = 0; ni < 4; ++ni)
                acc[mi][ni] = __builtin_amdgcn_mfma_f32_16x16x32_bf16(
                    af[mi], bfv[ni], acc[mi][ni], 0, 0, 0);
    }

    // epilogue: C/D frag mapping col=lane&15, row=(lane>>4)*4+reg
#pragma unroll
    for (int mi = 0; mi < 4; ++mi) {
#pragma unroll
        for (int ni = 0; ni < 4; ++ni) {
            int n = bn + wc*64 + ni*16 + lrow;
            if (n >= N) continue;
#pragma unroll
            for (int reg = 0; reg < 4; ++reg) {
                int m = bm + wr*64 + mi*16 + kg*4 + reg;
                float v = acc[mi][ni][reg];
                if (n < n_split) {
                    if (bias)  v += bias[n];
                    if (resid) v += resid[(long)m*ldr + n];
                    C[(long)m*ldc + n] = v;
                } else {
                    C2[(long)m*ldc2 + (n - n_split)] = v;
                }
            }
        }
    }
}

// ---------------------------------------------------------------------------
// Depthwise causal (dir=0) / anti-causal (dir=1) conv + bias + SiLU.
// Writes u (f32, for scan) and u_bf (bf16, for the combined GEMM).
__global__ __launch_bounds__(256) void conv_silu(
    const float* __restrict__ xz, const float* __restrict__ cw,
    const float* __restrict__ cb, float* __restrict__ u,
    ushort_t* __restrict__ ub, int dir)
{
    long idx = (long)blockIdx.x * 256 + threadIdx.x;
    if (idx >= (long)LL * DIN) return;
    int d  = (int)(idx % DIN);
    int l  = (int)(idx / DIN);
    float acc = cb[d];
#pragma unroll
    for (int k = 0; k < CD; ++k) {
        int j = dir ? (l + 3 - k) : (l - 3 + k);
        if (j >= 0 && j < LL)
            acc += cw[d*CD + k] * xz[(long)j*(2*DIN) + d];
    }
    float s = acc / (1.f + __expf(-acc));   // silu
    u[idx] = s;
    ub[idx] = f2bf(s);
}

// ---------------------------------------------------------------------------
// Chunked selective scan, pass 1: per (chunk, d, n) transfer pair
//   P = exp(An * sum(delta over chunk)),  S = chunk-local final state (h0=0).
__global__ __launch_bounds__(256) void scan_pass1(
    const float* __restrict__ u, const float* __restrict__ xz,
    const float* __restrict__ bc, const float* __restrict__ A_log,
    float* __restrict__ Pc, float* __restrict__ Sc, int dir)
{
    __shared__ float s_u[TCH][16];
    __shared__ float s_dl[TCH][16];
    __shared__ float s_B[TCH][16];
    int tid = threadIdx.x;
    int grp = tid >> 4;
    int n   = tid & 15;
    int d0  = (blockIdx.x % (DIN/16)) * 16;
    int c   = blockIdx.x / (DIN/16);
    int d   = d0 + grp;
    float An = -__expf(A_log[d*NST + n]);
    float h = 0.f, sumd = 0.f;
    int lc = tid & 15, lr = tid >> 4;
    for (int t0 = c*CH; t0 < (c+1)*CH; t0 += TCH) {
#pragma unroll
        for (int i = 0; i < 4; ++i) {
            int it = lr + i*16;
            int tau = t0 + it;
            int p = dir ? (LL-1-tau) : tau;
            s_u[it][lc] = u[(long)p*DIN + d0 + lc];
            float dp = xz[(long)p*(2*DIN) + d0 + lc];
            s_dl[it][lc] = (dp > 20.f) ? dp : log1pf(__expf(dp));
            s_B[it][lc] = bc[(long)p*NBC + lc];
        }
        __syncthreads();
#pragma unroll 4
        for (int i = 0; i < TCH; ++i) {
            float delta = s_dl[i][grp];
            float uv    = s_u[i][grp];
            float Bv    = s_B[i][n];
            h = __expf(delta * An) * h + delta*uv*Bv;
            sumd += delta;
        }
        __syncthreads();
    }
    long o = ((long)c*DIN + d)*NST + n;
    Pc[o] = __expf(An * sumd);
    Sc[o] = h;
}

// ---------------------------------------------------------------------------
// Chunked scan, mid: exclusive prefix over chunks per (d,n); Hin in place.
__global__ __launch_bounds__(256) void scan_mid(
    float* __restrict__ Pc, const float* __restrict__ Sc)
{
    int idx = blockIdx.x*256 + threadIdx.x;
    if (idx >= DIN*NST) return;
    float h = 0.f;
    for (int c = 0; c < NCH; ++c) {
        long o = (long)c*DIN*NST + idx;
        float p = Pc[o], s = Sc[o];
        Pc[o] = h;
        h = p*h + s;
    }
}

// ---------------------------------------------------------------------------
// Chunked scan, pass 2: re-run chunk from Hin; fused y+=D*u, y*=silu(z),
// writes gated y as bf16 (feeds the out GEMM).
__global__ __launch_bounds__(256) void scan_pass2(
    const float* __restrict__ u, const float* __restrict__ xz,
    const float* __restrict__ bc, const float* __restrict__ Hin,
    const float* __restrict__ A_log, const float* __restrict__ Dp,
    ushort_t* __restrict__ yg, int dir)
{
    __shared__ float s_u[TCH][16];
    __shared__ float s_dl[TCH][16];
    __shared__ float s_z[TCH][16];
    __shared__ float s_B[TCH][16];
    __shared__ float s_C[TCH][16];
    int tid = threadIdx.x;
    int grp = tid >> 4;
    int n   = tid & 15;
    int d0  = (blockIdx.x % (DIN/16)) * 16;
    int c   = blockIdx.x / (DIN/16);
    int d   = d0 + grp;
    float An = -__expf(A_log[d*NST + n]);
    float Dv = Dp[d];
    float h = Hin[((long)c*DIN + d)*NST + n];
    int lc = tid & 15, lr = tid >> 4;
    for (int t0 = c*CH; t0 < (c+1)*CH; t0 += TCH) {
#pragma unroll
        for (int i = 0; i < 4; ++i) {
            int it = lr + i*16;
            int tau = t0 + it;
            int p = dir ? (LL-1-tau) : tau;
            s_u[it][lc] = u[(long)p*DIN + d0 + lc];
            float dp = xz[(long)p*(2*DIN) + d0 + lc];
            s_dl[it][lc] = (dp > 20.f) ? dp : log1pf(__expf(dp));
            s_z[it][lc] = xz[(long)p*(2*DIN) + DIN + d0 + lc];
            s_B[it][lc] = bc[(long)p*NBC + lc];
            s_C[it][lc] = bc[(long)p*NBC + NST + lc];
        }
        __syncthreads();
#pragma unroll 4
        for (int i = 0; i < TCH; ++i) {
            float delta = s_dl[i][grp];
            float uv    = s_u[i][grp];
            float Bv    = s_B[i][n];
            float Cv    = s_C[i][n];
            h = __expf(delta * An) * h + delta*uv*Bv;
            float prod = h*Cv;
#pragma unroll
            for (int off = 8; off >= 1; off >>= 1) prod += __shfl_xor(prod, off);
            if (n == 0) {
                float yv = prod + Dv*uv;
                float z  = s_z[i][grp];
                s_z[i][grp] = yv * z / (1.f + __expf(-z));
            }
        }
        __syncthreads();
#pragma unroll
        for (int i = 0; i < 4; ++i) {
            int it = lr + i*16;
            int tau = t0 + it;
            int p = dir ? (LL-1-tau) : tau;
            yg[(long)p*DIN + d0 + lc] = f2bf(s_z[it][lc]);
        }
        __syncthreads();
    }
}

// ---------------------------------------------------------------------------
extern "C" void kernel_launch(void* const* d_in, const int* in_sizes, int n_in,
                              void* d_out, int out_size, void* d_ws, size_t ws_size,
                              hipStream_t stream)
{
    const float* x        = (const float*)d_in[0];
    const float* in_w     = (const float*)d_in[1];
    const float* conv_w   = (const float*)d_in[2];
    const float* conv_b   = (const float*)d_in[3];
    const float* xproj_w  = (const float*)d_in[4];
    const float* dt_w     = (const float*)d_in[5];
    const float* dt_b     = (const float*)d_in[6];
    const float* A_log    = (const float*)d_in[7];
    const float* Dp       = (const float*)d_in[8];
    const float* out_w    = (const float*)d_in[9];
    const float* ln_g     = (const float*)d_in[10];
    const float* ln_b     = (const float*)d_in[11];
    const float* fus_w    = (const float*)d_in[12];
    const float* fus_b    = (const float*)d_in[13];
    float* out = (float*)d_out;

    // workspace layout, ~88 MB total. f32 buffers first, then bf16.
    float* ws   = (float*)d_ws;
    float* xzc  = ws;                        // 2048*3072 = 6,291,456 f32
    float* uc   = xzc + (long)LL*2*DIN;      // 2048*1536 = 3,145,728
    float* bcb  = uc  + (long)LL*DIN;        // 2048*32   =    65,536
    float* Pc   = bcb + (long)LL*NBC;        // 16*1536*16=   393,216
    float* Sc   = Pc  + (long)NCH*DIN*NST;   // 16*1536*16=   393,216
    ushort_t* xn_bf  = (ushort_t*)(Sc + (long)NCH*DIN*NST);
    ushort_t* u_bf   = xn_bf  + (long)LL*DD;        // 2048*1536
    ushort_t* yg_bf  = u_bf   + (long)LL*DIN;       // 2048*1536
    ushort_t* in_w_bf= yg_bf  + (long)LL*DIN;       // 2*3072*768
    ushort_t* wdc_bf = in_w_bf+ 2L*2*DIN*DD;        // 2*1568*1536
    ushort_t* wc_bf  = wdc_bf + 2L*NCOMB*DIN;       // 2*768*1536
    ushort_t* owt_bf = wc_bf  + 2L*DD*DIN;          // 2*1536*768
    ushort_t* fus_bf = owt_bf + 2L*DIN*DD;          // 768*1536

    // ---- weight prep (per call, batch-independent) ----
    cvt_bf16<<<(DD*2*DD)/256, 256, 0, stream>>>(fus_w, fus_bf, (long)DD*2*DD);
    for (int dir = 0; dir < 2; ++dir) {
        cvt_bf16<<<(2*DIN*DD)/256, 256, 0, stream>>>(
            in_w + (long)dir*2*DIN*DD, in_w_bf + (long)dir*2*DIN*DD,
            (long)2*DIN*DD);
        wdcat_build<<<(NCOMB*DIN)/256, 256, 0, stream>>>(
            dt_w + (long)dir*DIN*RR, xproj_w + (long)dir*(RR+2*NST)*DIN,
            wdc_bf + (long)dir*NCOMB*DIN);
        owt_cvt<<<(DIN*DD)/256, 256, 0, stream>>>(
            out_w + (long)dir*DD*DIN, owt_bf + (long)dir*DIN*DD);
        // Wc[dir] = fus_w[:, dir*768:+768] @ out_w[dir]   (768 x 1536, K=768)
        gemm_mfma<<<dim3(12,6), 256, 0, stream>>>(
            fus_bf + dir*DD, owt_bf + (long)dir*DIN*DD, nullptr, nullptr,
            xzc, nullptr, DD, DIN, DD, 2*DD, DIN, 0, DIN, 0);
        cvt_bf16<<<(DD*DIN)/256, 256, 0, stream>>>(
            xzc, wc_bf + (long)dir*DD*DIN, (long)DD*DIN);
    }

    for (int b = 0; b < BB; ++b) {
        const float* xb = x + (long)b*LL*DD;
        float* outb = out + (long)b*LL*DD;
        ln_kernel<<<LL, 256, 0, stream>>>(xb, ln_g, ln_b, xn_bf);

        for (int dir = 0; dir < 2; ++dir) {
            // xz = xn @ in_w[dir].T   (2048 x 3072, K=768)
            gemm_mfma<<<dim3(24,16), 256, 0, stream>>>(
                xn_bf, in_w_bf + (long)dir*2*DIN*DD, nullptr, nullptr,
                xzc, nullptr, LL, 2*DIN, DD, DD, 2*DIN, 0, 2*DIN, 0);
            // u = silu(conv(xc) + cb)  -> f32 + bf16
            conv_silu<<<(LL*DIN)/256, 256, 0, stream>>>(
                xzc, conv_w + dir*DIN*CD, conv_b + dir*DIN, uc, u_bf, dir);
            // [delta_pre | B | C] = u @ Wcomb.T  (2048 x 1568, K=1536)
            gemm_mfma<<<dim3(13,16), 256, 0, stream>>>(
                u_bf, wdc_bf + (long)dir*NCOMB*DIN, dt_b + dir*DIN, nullptr,
                xzc, bcb, LL, NCOMB, DIN, DIN, 2*DIN, 0, DIN, NBC);
            // chunked selective scan
            scan_pass1<<<(DIN/16)*NCH, 256, 0, stream>>>(
                uc, xzc, bcb, A_log + (long)dir*DIN*NST, Pc, Sc, dir);
            scan_mid<<<(DIN*NST)/256, 256, 0, stream>>>(Pc, Sc);
            scan_pass2<<<(DIN/16)*NCH, 256, 0, stream>>>(
                uc, xzc, bcb, Pc, A_log + (long)dir*DIN*NST, Dp + dir*DIN,
                yg_bf, dir);
            // out: dir0: yg@Wc0^T + fus_b + x ; dir1: += yg@Wc1^T
            if (dir == 0) {
                gemm_mfma<<<dim3(6,16), 256, 0, stream>>>(
                    yg_bf, wc_bf, fus_b, xb,
                    outb, nullptr, LL, DD, DIN, DIN, DD, DD, DD, 0);
            } else {
                gemm_mfma<<<dim3(6,16), 256, 0, stream>>>(
                    yg_bf, wc_bf + (long)DD*DIN, nullptr, outb,
                    outb, nullptr, LL, DD, DIN, DIN, DD, DD, DD, 0);
            }
        }
    }
}

// Round 6
// 1760.419 us; speedup vs baseline: 6.0731x; 1.2212x over previous
//
#include <hip/hip_runtime.h>
#include <hip/hip_bf16.h>

// Problem constants
#define BB 4
#define LL 2048
#define DD 768
#define DIN 1536
#define NST 16
#define CD 4
#define RR 48
#define NBC 32          // B,C columns (2*NST)
#define NCOMB (DIN+NBC) // 1568: combined [delta | B | C] GEMM width
#define CH2 64          // scan chunk length
#define NCH2 (LL/CH2)   // 32 chunks
#define DPB 64          // d-channels per scan block
#define LOG2E 1.44269504088896f

typedef unsigned short ushort_t;
typedef unsigned int u32;
typedef __attribute__((ext_vector_type(4))) float f32x4;
typedef __attribute__((ext_vector_type(8))) short bf16x8;
typedef __attribute__((ext_vector_type(4))) ushort_t u16x4;

static __device__ __forceinline__ ushort_t f2bf(float f) {
    unsigned int u = __float_as_uint(f);
    u += 0x7FFF + ((u >> 16) & 1);          // RNE
    return (ushort_t)(u >> 16);
}

static __device__ __forceinline__ void gload_lds16(const void* g, void* l) {
    __builtin_amdgcn_global_load_lds(
        (const __attribute__((address_space(1))) u32*)g,
        (__attribute__((address_space(3))) u32*)l, 16, 0, 0);
}

// ---------------------------------------------------------------------------
// LayerNorm over last dim (768). One block (256 thr) per row. bf16 output.
__global__ __launch_bounds__(256) void ln_kernel(
    const float* __restrict__ x, const float* __restrict__ g,
    const float* __restrict__ b, ushort_t* __restrict__ xn)
{
    int row = blockIdx.x;
    const float* xr = x + (long)row * DD;
    int t = threadIdx.x;
    float v[3];
    float s = 0.f;
#pragma unroll
    for (int i = 0; i < 3; ++i) { v[i] = xr[t + i*256]; s += v[i]; }
#pragma unroll
    for (int off = 32; off >= 1; off >>= 1) s += __shfl_xor(s, off);
    __shared__ float red[4], red2[4];
    int wid = t >> 6;
    if ((t & 63) == 0) red[wid] = s;
    __syncthreads();
    float mean = (red[0]+red[1]+red[2]+red[3]) * (1.f/768.f);
    float vs = 0.f;
#pragma unroll
    for (int i = 0; i < 3; ++i) { float d0 = v[i]-mean; vs += d0*d0; }
#pragma unroll
    for (int off = 32; off >= 1; off >>= 1) vs += __shfl_xor(vs, off);
    if ((t & 63) == 0) red2[wid] = vs;
    __syncthreads();
    float var = (red2[0]+red2[1]+red2[2]+red2[3]) * (1.f/768.f);
    float rstd = rsqrtf(var + 1e-5f);
    ushort_t* xo = xn + (long)row * DD;
#pragma unroll
    for (int i = 0; i < 3; ++i) {
        int c = t + i*256;
        xo[c] = f2bf((v[i]-mean)*rstd*g[c] + b[c]);
    }
}

// ---------------------------------------------------------------------------
// elementwise f32 -> bf16 convert
__global__ __launch_bounds__(256) void cvt_bf16(
    const float* __restrict__ in, ushort_t* __restrict__ out, long n)
{
    long i = (long)blockIdx.x*256 + threadIdx.x;
    if (i < n) out[i] = f2bf(in[i]);
}

// ---------------------------------------------------------------------------
// transpose-convert out_w (DD x DIN, row-major) -> owt (DIN x DD) bf16
__global__ __launch_bounds__(256) void owt_cvt(
    const float* __restrict__ ow, ushort_t* __restrict__ out)
{
    long idx = (long)blockIdx.x*256 + threadIdx.x;
    if (idx >= (long)DIN*DD) return;
    int k = (int)(idx % DD);   // source row
    int n = (int)(idx / DD);   // source col
    out[idx] = f2bf(ow[(long)k*DIN + n]);
}

// ---------------------------------------------------------------------------
// Build combined [Wdc | xw_B | xw_C] bf16 weight (NCOMB x DIN)
__global__ __launch_bounds__(256) void wdcat_build(
    const float* __restrict__ dt_w, const float* __restrict__ xw,
    ushort_t* __restrict__ out)
{
    long idx = (long)blockIdx.x*256 + threadIdx.x;
    if (idx >= (long)NCOMB*DIN) return;
    int k = (int)(idx % DIN);
    int d = (int)(idx / DIN);
    float acc;
    if (d < DIN) {
        acc = 0.f;
#pragma unroll 8
        for (int r = 0; r < RR; ++r)
            acc += dt_w[d*RR + r] * xw[(long)r*DIN + k];
    } else {
        acc = xw[(long)(RR + d - DIN)*DIN + k];
    }
    out[idx] = f2bf(acc);
}

// ---------------------------------------------------------------------------
// MFMA GEMM, bf16 x bf16 -> f32 (unchanged from round 5)
__global__ __launch_bounds__(256) void gemm_mfma(
    const ushort_t* __restrict__ A, const ushort_t* __restrict__ Wb,
    const float* __restrict__ bias, const float* __restrict__ resid,
    float* __restrict__ C, float* __restrict__ C2,
    int M, int N, int K, int lda, int ldc, int ldr, int n_split, int ldc2)
{
    __shared__ __attribute__((aligned(16))) ushort_t As[128*32];
    __shared__ __attribute__((aligned(16))) ushort_t Bs[128*32];
    int tid = threadIdx.x;
    int bm = blockIdx.y * 128, bn = blockIdx.x * 128;
    int lane = tid & 63, w = tid >> 6;
    int wr = w >> 1, wc = w & 1;
    int lrow = lane & 15, kg = lane >> 4;
    int srowA = lane >> 2;
    int sc8  = lane & 3;

    f32x4 acc[4][4] = {};

    for (int k0 = 0; k0 < K; k0 += 32) {
        __syncthreads();
#pragma unroll
        for (int it = 0; it < 2; ++it) {
            int chunk = it*4 + w;
            int row = chunk*16 + srowA;
            gload_lds16(&A[(long)(bm+row)*lda + k0 + sc8*8], &As[chunk*512]);
        }
#pragma unroll
        for (int it = 0; it < 2; ++it) {
            int chunk = it*4 + w;
            int row = chunk*16 + srowA;
            int n = bn + row; if (n > N-1) n = N-1;
            gload_lds16(&Wb[(long)n*K + k0 + sc8*8], &Bs[chunk*512]);
        }
        __syncthreads();
        bf16x8 af[4], bfv[4];
#pragma unroll
        for (int mi = 0; mi < 4; ++mi)
            af[mi] = *(const bf16x8*)&As[(wr*64 + mi*16 + lrow)*32 + kg*8];
#pragma unroll
        for (int ni = 0; ni < 4; ++ni)
            bfv[ni] = *(const bf16x8*)&Bs[(wc*64 + ni*16 + lrow)*32 + kg*8];
#pragma unroll
        for (int mi = 0; mi < 4; ++mi)
#pragma unroll
            for (int ni = 0; ni < 4; ++ni)
                acc[mi][ni] = __builtin_amdgcn_mfma_f32_16x16x32_bf16(
                    af[mi], bfv[ni], acc[mi][ni], 0, 0, 0);
    }

#pragma unroll
    for (int mi = 0; mi < 4; ++mi) {
#pragma unroll
        for (int ni = 0; ni < 4; ++ni) {
            int n = bn + wc*64 + ni*16 + lrow;
            if (n >= N) continue;
#pragma unroll
            for (int reg = 0; reg < 4; ++reg) {
                int m = bm + wr*64 + mi*16 + kg*4 + reg;
                float v = acc[mi][ni][reg];
                if (n < n_split) {
                    if (bias)  v += bias[n];
                    if (resid) v += resid[(long)m*ldr + n];
                    C[(long)m*ldc + n] = v;
                } else {
                    C2[(long)m*ldc2 + (n - n_split)] = v;
                }
            }
        }
    }
}

// ---------------------------------------------------------------------------
// Depthwise causal/anti-causal conv + bias + SiLU, float4-vectorized over d.
// One thread = 4 consecutive channels at one timestep.
__global__ __launch_bounds__(256) void conv_silu(
    const float* __restrict__ xz, const float* __restrict__ cw,
    const float* __restrict__ cb, float* __restrict__ u,
    ushort_t* __restrict__ ub, int dir)
{
    long idx4 = (long)blockIdx.x * 256 + threadIdx.x;   // LL*DIN/4 total
    int dq = (int)(idx4 % (DIN/4));
    int l  = (int)(idx4 / (DIN/4));
    int d  = dq * 4;
    f32x4 acc = *(const f32x4*)&cb[d];
    f32x4 w0 = *(const f32x4*)&cw[(d+0)*CD];
    f32x4 w1 = *(const f32x4*)&cw[(d+1)*CD];
    f32x4 w2 = *(const f32x4*)&cw[(d+2)*CD];
    f32x4 w3 = *(const f32x4*)&cw[(d+3)*CD];
#pragma unroll
    for (int k = 0; k < CD; ++k) {
        int j = dir ? (l + 3 - k) : (l - 3 + k);
        if (j >= 0 && j < LL) {
            f32x4 xv = *(const f32x4*)&xz[(long)j*(2*DIN) + d];
            acc[0] += w0[k]*xv[0];
            acc[1] += w1[k]*xv[1];
            acc[2] += w2[k]*xv[2];
            acc[3] += w3[k]*xv[3];
        }
    }
    f32x4 s;
    u16x4 o;
#pragma unroll
    for (int e = 0; e < 4; ++e) {
        s[e] = acc[e] / (1.f + __expf(-acc[e]));
        o[e] = f2bf(s[e]);
    }
    *(f32x4*)&u[idx4*4] = s;
    *(u16x4*)&ub[idx4*4] = o;
}

// ---------------------------------------------------------------------------
// Chunked selective scan, pass 1. Block = 256 thr = 64 d x 4 n-groups
// (4 states per thread). One chunk of CH2=64 steps per block.
// Also softplus's delta IN PLACE in xz (pass2 reuses).
__global__ __launch_bounds__(256) void scan_pass1(
    const float* __restrict__ u, float* __restrict__ xz,
    const float* __restrict__ bc, const float* __restrict__ A_log,
    float* __restrict__ Pc, float* __restrict__ Sc, int dir)
{
    __shared__ float s_u[CH2][DPB];
    __shared__ float s_dl[CH2][DPB];
    __shared__ float s_B[CH2][16];
    int t = threadIdx.x;
    int d0 = (blockIdx.x % (DIN/DPB)) * DPB;
    int c  = blockIdx.x / (DIN/DPB);
    int scol = (t & 15) * 4;
#pragma unroll
    for (int i = 0; i < 4; ++i) {
        int row = (t >> 4) + i*16;
        int tau = c*CH2 + row;
        int p = dir ? (LL-1-tau) : tau;
        *(f32x4*)&s_u[row][scol] = *(const f32x4*)&u[(long)p*DIN + d0 + scol];
        float* dptr = &xz[(long)p*(2*DIN) + d0 + scol];
        f32x4 vd = *(const f32x4*)dptr;
        f32x4 sp;
#pragma unroll
        for (int e = 0; e < 4; ++e)
            sp[e] = (vd[e] > 20.f) ? vd[e] : log1pf(__expf(vd[e]));
        *(f32x4*)&s_dl[row][scol] = sp;
        *(f32x4*)dptr = sp;                  // write back for pass2
    }
    {
        int row = t >> 2, col = (t & 3)*4;
        int tau = c*CH2 + row;
        int p = dir ? (LL-1-tau) : tau;
        *(f32x4*)&s_B[row][col] = *(const f32x4*)&bc[(long)p*NBC + col];
    }
    __syncthreads();
    int dloc = t >> 2, ng = t & 3;
    int d = d0 + dloc;
    f32x4 Alv = *(const f32x4*)&A_log[d*NST + ng*4];
    float An2[4];
#pragma unroll
    for (int j = 0; j < 4; ++j) An2[j] = -__expf(Alv[j]) * LOG2E;
    float h[4] = {0.f, 0.f, 0.f, 0.f};
    float sumd = 0.f;
#pragma unroll 4
    for (int i = 0; i < CH2; ++i) {
        float delta = s_dl[i][dloc];
        float du = delta * s_u[i][dloc];
        f32x4 Bv = *(const f32x4*)&s_B[i][ng*4];
#pragma unroll
        for (int j = 0; j < 4; ++j)
            h[j] = exp2f(delta*An2[j])*h[j] + du*Bv[j];
        sumd += delta;
    }
    long o = ((long)c*DIN + d)*NST + ng*4;
    f32x4 pv, sv;
#pragma unroll
    for (int j = 0; j < 4; ++j) { pv[j] = exp2f(An2[j]*sumd); sv[j] = h[j]; }
    *(f32x4*)&Pc[o] = pv;
    *(f32x4*)&Sc[o] = sv;
}

// ---------------------------------------------------------------------------
// Chunked scan, mid: exclusive prefix over chunks per (d,n); Hin in place.
__global__ __launch_bounds__(256) void scan_mid(
    float* __restrict__ Pc, const float* __restrict__ Sc)
{
    int idx = blockIdx.x*256 + threadIdx.x;
    if (idx >= DIN*NST) return;
    float h = 0.f;
    for (int c = 0; c < NCH2; ++c) {
        long o = (long)c*DIN*NST + idx;
        float p = Pc[o], s = Sc[o];
        Pc[o] = h;
        h = p*h + s;
    }
}

// ---------------------------------------------------------------------------
// Chunked scan, pass 2: re-run chunk from Hin (delta already softplus'ed by
// pass1). Fused y+=D*u and y*=silu(z) (z read coalesced in gate phase).
// Writes gated y as bf16.
__global__ __launch_bounds__(256) void scan_pass2(
    const float* __restrict__ u, const float* __restrict__ xz,
    const float* __restrict__ bc, const float* __restrict__ Hin,
    const float* __restrict__ A_log, const float* __restrict__ Dp,
    ushort_t* __restrict__ yg, int dir)
{
    __shared__ float s_u[CH2][DPB];
    __shared__ float s_dl[CH2][DPB];    // delta; y written over it
    __shared__ float s_B[CH2][16];
    __shared__ float s_C[CH2][16];
    int t = threadIdx.x;
    int d0 = (blockIdx.x % (DIN/DPB)) * DPB;
    int c  = blockIdx.x / (DIN/DPB);
    int scol = (t & 15) * 4;
#pragma unroll
    for (int i = 0; i < 4; ++i) {
        int row = (t >> 4) + i*16;
        int tau = c*CH2 + row;
        int p = dir ? (LL-1-tau) : tau;
        *(f32x4*)&s_u[row][scol]  = *(const f32x4*)&u[(long)p*DIN + d0 + scol];
        *(f32x4*)&s_dl[row][scol] = *(const f32x4*)&xz[(long)p*(2*DIN) + d0 + scol];
    }
    {
        int row = t >> 2, col = (t & 3)*4;
        int tau = c*CH2 + row;
        int p = dir ? (LL-1-tau) : tau;
        *(f32x4*)&s_B[row][col] = *(const f32x4*)&bc[(long)p*NBC + col];
        *(f32x4*)&s_C[row][col] = *(const f32x4*)&bc[(long)p*NBC + NST + col];
    }
    __syncthreads();
    int dloc = t >> 2, ng = t & 3;
    int d = d0 + dloc;
    f32x4 Alv = *(const f32x4*)&A_log[d*NST + ng*4];
    float An2[4];
#pragma unroll
    for (int j = 0; j < 4; ++j) An2[j] = -__expf(Alv[j]) * LOG2E;
    float Dv = Dp[d];
    f32x4 hv = *(const f32x4*)&Hin[((long)c*DIN + d)*NST + ng*4];
    float h[4] = {hv[0], hv[1], hv[2], hv[3]};
#pragma unroll 4
    for (int i = 0; i < CH2; ++i) {
        float delta = s_dl[i][dloc];
        float uv    = s_u[i][dloc];
        float du    = delta * uv;
        f32x4 Bv = *(const f32x4*)&s_B[i][ng*4];
        f32x4 Cv = *(const f32x4*)&s_C[i][ng*4];
        float prod = 0.f;
#pragma unroll
        for (int j = 0; j < 4; ++j) {
            h[j] = exp2f(delta*An2[j])*h[j] + du*Bv[j];
            prod += h[j]*Cv[j];
        }
        prod += __shfl_xor(prod, 1);
        prod += __shfl_xor(prod, 2);
        if (ng == 0) s_dl[i][dloc] = prod + Dv*uv;   // y over dead delta slot
    }
    __syncthreads();
    // gate phase: y *= silu(z), write bf16, coalesced
#pragma unroll
    for (int i = 0; i < 4; ++i) {
        int row = (t >> 4) + i*16;
        int tau = c*CH2 + row;
        int p = dir ? (LL-1-tau) : tau;
        f32x4 z4 = *(const f32x4*)&xz[(long)p*(2*DIN) + DIN + d0 + scol];
        u16x4 o;
#pragma unroll
        for (int e = 0; e < 4; ++e) {
            float y = s_dl[row][scol + e];
            float z = z4[e];
            o[e] = f2bf(y * z / (1.f + __expf(-z)));
        }
        *(u16x4*)&yg[(long)p*DIN + d0 + scol] = o;
    }
}

// ---------------------------------------------------------------------------
extern "C" void kernel_launch(void* const* d_in, const int* in_sizes, int n_in,
                              void* d_out, int out_size, void* d_ws, size_t ws_size,
                              hipStream_t stream)
{
    const float* x        = (const float*)d_in[0];
    const float* in_w     = (const float*)d_in[1];
    const float* conv_w   = (const float*)d_in[2];
    const float* conv_b   = (const float*)d_in[3];
    const float* xproj_w  = (const float*)d_in[4];
    const float* dt_w     = (const float*)d_in[5];
    const float* dt_b     = (const float*)d_in[6];
    const float* A_log    = (const float*)d_in[7];
    const float* Dp       = (const float*)d_in[8];
    const float* out_w    = (const float*)d_in[9];
    const float* ln_g     = (const float*)d_in[10];
    const float* ln_b     = (const float*)d_in[11];
    const float* fus_w    = (const float*)d_in[12];
    const float* fus_b    = (const float*)d_in[13];
    float* out = (float*)d_out;

    // workspace layout, ~91 MB total. f32 buffers first, then bf16.
    float* ws   = (float*)d_ws;
    float* xzc  = ws;                        // 2048*3072 = 6,291,456 f32
    float* uc   = xzc + (long)LL*2*DIN;      // 2048*1536 = 3,145,728
    float* bcb  = uc  + (long)LL*DIN;        // 2048*32   =    65,536
    float* Pc   = bcb + (long)LL*NBC;        // 32*1536*16=   786,432
    float* Sc   = Pc  + (long)NCH2*DIN*NST;  // 32*1536*16=   786,432
    ushort_t* xn_bf  = (ushort_t*)(Sc + (long)NCH2*DIN*NST);
    ushort_t* u_bf   = xn_bf  + (long)LL*DD;        // 2048*1536
    ushort_t* yg_bf  = u_bf   + (long)LL*DIN;       // 2048*1536
    ushort_t* in_w_bf= yg_bf  + (long)LL*DIN;       // 2*3072*768
    ushort_t* wdc_bf = in_w_bf+ 2L*2*DIN*DD;        // 2*1568*1536
    ushort_t* wc_bf  = wdc_bf + 2L*NCOMB*DIN;       // 2*768*1536
    ushort_t* owt_bf = wc_bf  + 2L*DD*DIN;          // 2*1536*768
    ushort_t* fus_bf = owt_bf + 2L*DIN*DD;          // 768*1536

    // ---- weight prep (per call, batch-independent) ----
    cvt_bf16<<<(DD*2*DD)/256, 256, 0, stream>>>(fus_w, fus_bf, (long)DD*2*DD);
    for (int dir = 0; dir < 2; ++dir) {
        cvt_bf16<<<(2*DIN*DD)/256, 256, 0, stream>>>(
            in_w + (long)dir*2*DIN*DD, in_w_bf + (long)dir*2*DIN*DD,
            (long)2*DIN*DD);
        wdcat_build<<<(NCOMB*DIN)/256, 256, 0, stream>>>(
            dt_w + (long)dir*DIN*RR, xproj_w + (long)dir*(RR+2*NST)*DIN,
            wdc_bf + (long)dir*NCOMB*DIN);
        owt_cvt<<<(DIN*DD)/256, 256, 0, stream>>>(
            out_w + (long)dir*DD*DIN, owt_bf + (long)dir*DIN*DD);
        gemm_mfma<<<dim3(12,6), 256, 0, stream>>>(
            fus_bf + dir*DD, owt_bf + (long)dir*DIN*DD, nullptr, nullptr,
            xzc, nullptr, DD, DIN, DD, 2*DD, DIN, 0, DIN, 0);
        cvt_bf16<<<(DD*DIN)/256, 256, 0, stream>>>(
            xzc, wc_bf + (long)dir*DD*DIN, (long)DD*DIN);
    }

    for (int b = 0; b < BB; ++b) {
        const float* xb = x + (long)b*LL*DD;
        float* outb = out + (long)b*LL*DD;
        ln_kernel<<<LL, 256, 0, stream>>>(xb, ln_g, ln_b, xn_bf);

        for (int dir = 0; dir < 2; ++dir) {
            // xz = xn @ in_w[dir].T   (2048 x 3072, K=768)
            gemm_mfma<<<dim3(24,16), 256, 0, stream>>>(
                xn_bf, in_w_bf + (long)dir*2*DIN*DD, nullptr, nullptr,
                xzc, nullptr, LL, 2*DIN, DD, DD, 2*DIN, 0, 2*DIN, 0);
            // u = silu(conv(xc) + cb)  -> f32 + bf16
            conv_silu<<<(LL*DIN/4)/256, 256, 0, stream>>>(
                xzc, conv_w + dir*DIN*CD, conv_b + dir*DIN, uc, u_bf, dir);
            // [delta_pre | B | C] = u @ Wcomb.T  (2048 x 1568, K=1536)
            gemm_mfma<<<dim3(13,16), 256, 0, stream>>>(
                u_bf, wdc_bf + (long)dir*NCOMB*DIN, dt_b + dir*DIN, nullptr,
                xzc, bcb, LL, NCOMB, DIN, DIN, 2*DIN, 0, DIN, NBC);
            // chunked selective scan
            scan_pass1<<<(DIN/DPB)*NCH2, 256, 0, stream>>>(
                uc, xzc, bcb, A_log + (long)dir*DIN*NST, Pc, Sc, dir);
            scan_mid<<<(DIN*NST)/256, 256, 0, stream>>>(Pc, Sc);
            scan_pass2<<<(DIN/DPB)*NCH2, 256, 0, stream>>>(
                uc, xzc, bcb, Pc, A_log + (long)dir*DIN*NST, Dp + dir*DIN,
                yg_bf, dir);
            // out: dir0: yg@Wc0^T + fus_b + x ; dir1: += yg@Wc1^T
            if (dir == 0) {
                gemm_mfma<<<dim3(6,16), 256, 0, stream>>>(
                    yg_bf, wc_bf, fus_b, xb,
                    outb, nullptr, LL, DD, DIN, DIN, DD, DD, DD, 0);
            } else {
                gemm_mfma<<<dim3(6,16), 256, 0, stream>>>(
                    yg_bf, wc_bf + (long)DD*DIN, nullptr, outb,
                    outb, nullptr, LL, DD, DIN, DIN, DD, DD, DD, 0);
            }
        }
    }
}

// Round 7
// 1375.009 us; speedup vs baseline: 7.7753x; 1.2803x over previous
//
#include <hip/hip_runtime.h>
#include <hip/hip_bf16.h>

// Problem constants
#define BB 4
#define LL 2048
#define DD 768
#define DIN 1536
#define NST 16
#define CD 4
#define RR 48
#define NBC 32          // B,C columns (2*NST)
#define NCOMB (DIN+NBC) // 1568: combined [delta | B | C] GEMM width
#define CH2 64          // scan chunk length
#define NCH2 (LL/CH2)   // 32 chunks
#define DPB 64          // d-channels per scan block
#define LOG2E 1.44269504088896f

typedef unsigned short ushort_t;
typedef unsigned int u32;
typedef __attribute__((ext_vector_type(4))) float f32x4;
typedef __attribute__((ext_vector_type(8))) short bf16x8;
typedef __attribute__((ext_vector_type(4))) ushort_t u16x4;

static __device__ __forceinline__ ushort_t f2bf(float f) {
    unsigned int u = __float_as_uint(f);
    u += 0x7FFF + ((u >> 16) & 1);          // RNE
    return (ushort_t)(u >> 16);
}

static __device__ __forceinline__ void gload_lds16(const void* g, void* l) {
    __builtin_amdgcn_global_load_lds(
        (const __attribute__((address_space(1))) u32*)g,
        (__attribute__((address_space(3))) u32*)l, 16, 0, 0);
}

// ---------------------------------------------------------------------------
// LayerNorm over last dim (768). One block (256 thr) per row. bf16 output.
__global__ __launch_bounds__(256) void ln_kernel(
    const float* __restrict__ x, const float* __restrict__ g,
    const float* __restrict__ b, ushort_t* __restrict__ xn)
{
    int row = blockIdx.x;
    const float* xr = x + (long)row * DD;
    int t = threadIdx.x;
    float v[3];
    float s = 0.f;
#pragma unroll
    for (int i = 0; i < 3; ++i) { v[i] = xr[t + i*256]; s += v[i]; }
#pragma unroll
    for (int off = 32; off >= 1; off >>= 1) s += __shfl_xor(s, off);
    __shared__ float red[4], red2[4];
    int wid = t >> 6;
    if ((t & 63) == 0) red[wid] = s;
    __syncthreads();
    float mean = (red[0]+red[1]+red[2]+red[3]) * (1.f/768.f);
    float vs = 0.f;
#pragma unroll
    for (int i = 0; i < 3; ++i) { float d0 = v[i]-mean; vs += d0*d0; }
#pragma unroll
    for (int off = 32; off >= 1; off >>= 1) vs += __shfl_xor(vs, off);
    if ((t & 63) == 0) red2[wid] = vs;
    __syncthreads();
    float var = (red2[0]+red2[1]+red2[2]+red2[3]) * (1.f/768.f);
    float rstd = rsqrtf(var + 1e-5f);
    ushort_t* xo = xn + (long)row * DD;
#pragma unroll
    for (int i = 0; i < 3; ++i) {
        int c = t + i*256;
        xo[c] = f2bf((v[i]-mean)*rstd*g[c] + b[c]);
    }
}

// ---------------------------------------------------------------------------
// elementwise f32 -> bf16 convert
__global__ __launch_bounds__(256) void cvt_bf16(
    const float* __restrict__ in, ushort_t* __restrict__ out, long n)
{
    long i = (long)blockIdx.x*256 + threadIdx.x;
    if (i < n) out[i] = f2bf(in[i]);
}

// ---------------------------------------------------------------------------
// transpose-convert out_w (DD x DIN, row-major) -> owt (DIN x DD) bf16
__global__ __launch_bounds__(256) void owt_cvt(
    const float* __restrict__ ow, ushort_t* __restrict__ out)
{
    long idx = (long)blockIdx.x*256 + threadIdx.x;
    if (idx >= (long)DIN*DD) return;
    int k = (int)(idx % DD);   // source row
    int n = (int)(idx / DD);   // source col
    out[idx] = f2bf(ow[(long)k*DIN + n]);
}

// ---------------------------------------------------------------------------
// Build combined [Wdc | xw_B | xw_C] bf16 weight (NCOMB x DIN)
__global__ __launch_bounds__(256) void wdcat_build(
    const float* __restrict__ dt_w, const float* __restrict__ xw,
    ushort_t* __restrict__ out)
{
    long idx = (long)blockIdx.x*256 + threadIdx.x;
    if (idx >= (long)NCOMB*DIN) return;
    int k = (int)(idx % DIN);
    int d = (int)(idx / DIN);
    float acc;
    if (d < DIN) {
        acc = 0.f;
#pragma unroll 8
        for (int r = 0; r < RR; ++r)
            acc += dt_w[d*RR + r] * xw[(long)r*DIN + k];
    } else {
        acc = xw[(long)(RR + d - DIN)*DIN + k];
    }
    out[idx] = f2bf(acc);
}

// ---------------------------------------------------------------------------
// MFMA GEMM, bf16 x bf16 -> f32. Double-buffered LDS, ONE barrier per K-step:
//   syncthreads (drains prev-issued loads for cur buf) -> issue next-tile
//   global_load_lds -> ds_read + MFMA on cur buf.
// 128x128 tile, BK=32, 256 thr = 4 waves (2x2 of 64x64), 16x16x32 MFMA.
// Requires M%128==0, K%32==0. B rows clamped to N-1 (cols >=N discarded).
// Split epilogue: n<n_split -> C (+bias,+resid); n>=n_split -> C2.
__global__ __launch_bounds__(256) void gemm_mfma(
    const ushort_t* __restrict__ A, const ushort_t* __restrict__ Wb,
    const float* __restrict__ bias, const float* __restrict__ resid,
    float* __restrict__ C, float* __restrict__ C2,
    int M, int N, int K, int lda, int ldc, int ldr, int n_split, int ldc2)
{
    __shared__ __attribute__((aligned(16))) ushort_t As[2][128*32];
    __shared__ __attribute__((aligned(16))) ushort_t Bs[2][128*32];
    int tid = threadIdx.x;
    int bm = blockIdx.y * 128, bn = blockIdx.x * 128;
    int lane = tid & 63, w = tid >> 6;
    int wr = w >> 1, wc = w & 1;
    int lrow = lane & 15, kg = lane >> 4;
    int srowA = lane >> 2;          // 0..15 within chunk
    int sc8  = lane & 3;            // 16B slot within 64B row

    auto stage = [&](int buf, int kk) {
#pragma unroll
        for (int it = 0; it < 2; ++it) {
            int chunk = it*4 + w;                  // 0..7 (wave-uniform)
            int row = chunk*16 + srowA;            // 0..127
            gload_lds16(&A[(long)(bm+row)*lda + kk + sc8*8],
                        &As[buf][chunk*512]);
        }
#pragma unroll
        for (int it = 0; it < 2; ++it) {
            int chunk = it*4 + w;
            int row = chunk*16 + srowA;
            int n = bn + row; if (n > N-1) n = N-1;
            gload_lds16(&Wb[(long)n*K + kk + sc8*8],
                        &Bs[buf][chunk*512]);
        }
    };

    f32x4 acc[4][4] = {};
    int nt = K >> 5;
    stage(0, 0);                    // prologue

    for (int t = 0; t < nt; ++t) {
        int cur = t & 1;
        __syncthreads();            // vmcnt(0)+barrier: buf[cur] staged,
                                    // prior reads of buf[cur^1] retired
        if (t + 1 < nt) stage(cur ^ 1, (t + 1) << 5);
        bf16x8 af[4], bfv[4];
#pragma unroll
        for (int mi = 0; mi < 4; ++mi)
            af[mi] = *(const bf16x8*)&As[cur][(wr*64 + mi*16 + lrow)*32 + kg*8];
#pragma unroll
        for (int ni = 0; ni < 4; ++ni)
            bfv[ni] = *(const bf16x8*)&Bs[cur][(wc*64 + ni*16 + lrow)*32 + kg*8];
#pragma unroll
        for (int mi = 0; mi < 4; ++mi)
#pragma unroll
            for (int ni = 0; ni < 4; ++ni)
                acc[mi][ni] = __builtin_amdgcn_mfma_f32_16x16x32_bf16(
                    af[mi], bfv[ni], acc[mi][ni], 0, 0, 0);
    }

    // epilogue: C/D frag mapping col=lane&15, row=(lane>>4)*4+reg
#pragma unroll
    for (int mi = 0; mi < 4; ++mi) {
#pragma unroll
        for (int ni = 0; ni < 4; ++ni) {
            int n = bn + wc*64 + ni*16 + lrow;
            if (n >= N) continue;
#pragma unroll
            for (int reg = 0; reg < 4; ++reg) {
                int m = bm + wr*64 + mi*16 + kg*4 + reg;
                float v = acc[mi][ni][reg];
                if (n < n_split) {
                    if (bias)  v += bias[n];
                    if (resid) v += resid[(long)m*ldr + n];
                    C[(long)m*ldc + n] = v;
                } else {
                    C2[(long)m*ldc2 + (n - n_split)] = v;
                }
            }
        }
    }
}

// ---------------------------------------------------------------------------
// Depthwise causal/anti-causal conv + bias + SiLU, float4-vectorized over d.
__global__ __launch_bounds__(256) void conv_silu(
    const float* __restrict__ xz, const float* __restrict__ cw,
    const float* __restrict__ cb, float* __restrict__ u,
    ushort_t* __restrict__ ub, int dir)
{
    long idx4 = (long)blockIdx.x * 256 + threadIdx.x;   // LL*DIN/4 total
    int dq = (int)(idx4 % (DIN/4));
    int l  = (int)(idx4 / (DIN/4));
    int d  = dq * 4;
    f32x4 acc = *(const f32x4*)&cb[d];
    f32x4 w0 = *(const f32x4*)&cw[(d+0)*CD];
    f32x4 w1 = *(const f32x4*)&cw[(d+1)*CD];
    f32x4 w2 = *(const f32x4*)&cw[(d+2)*CD];
    f32x4 w3 = *(const f32x4*)&cw[(d+3)*CD];
#pragma unroll
    for (int k = 0; k < CD; ++k) {
        int j = dir ? (l + 3 - k) : (l - 3 + k);
        if (j >= 0 && j < LL) {
            f32x4 xv = *(const f32x4*)&xz[(long)j*(2*DIN) + d];
            acc[0] += w0[k]*xv[0];
            acc[1] += w1[k]*xv[1];
            acc[2] += w2[k]*xv[2];
            acc[3] += w3[k]*xv[3];
        }
    }
    f32x4 s;
    u16x4 o;
#pragma unroll
    for (int e = 0; e < 4; ++e) {
        s[e] = acc[e] / (1.f + __expf(-acc[e]));
        o[e] = f2bf(s[e]);
    }
    *(f32x4*)&u[idx4*4] = s;
    *(u16x4*)&ub[idx4*4] = o;
}

// ---------------------------------------------------------------------------
// Chunked selective scan, pass 1. Block = 256 thr = 64 d x 4 n-groups
// (4 states per thread). One chunk of CH2=64 steps per block.
// Also softplus's delta IN PLACE in xz (pass2 reuses).
__global__ __launch_bounds__(256) void scan_pass1(
    const float* __restrict__ u, float* __restrict__ xz,
    const float* __restrict__ bc, const float* __restrict__ A_log,
    float* __restrict__ Pc, float* __restrict__ Sc, int dir)
{
    __shared__ float s_u[CH2][DPB];
    __shared__ float s_dl[CH2][DPB];
    __shared__ float s_B[CH2][16];
    int t = threadIdx.x;
    int d0 = (blockIdx.x % (DIN/DPB)) * DPB;
    int c  = blockIdx.x / (DIN/DPB);
    int scol = (t & 15) * 4;
#pragma unroll
    for (int i = 0; i < 4; ++i) {
        int row = (t >> 4) + i*16;
        int tau = c*CH2 + row;
        int p = dir ? (LL-1-tau) : tau;
        *(f32x4*)&s_u[row][scol] = *(const f32x4*)&u[(long)p*DIN + d0 + scol];
        float* dptr = &xz[(long)p*(2*DIN) + d0 + scol];
        f32x4 vd = *(const f32x4*)dptr;
        f32x4 sp;
#pragma unroll
        for (int e = 0; e < 4; ++e)
            sp[e] = (vd[e] > 20.f) ? vd[e] : log1pf(__expf(vd[e]));
        *(f32x4*)&s_dl[row][scol] = sp;
        *(f32x4*)dptr = sp;                  // write back for pass2
    }
    {
        int row = t >> 2, col = (t & 3)*4;
        int tau = c*CH2 + row;
        int p = dir ? (LL-1-tau) : tau;
        *(f32x4*)&s_B[row][col] = *(const f32x4*)&bc[(long)p*NBC + col];
    }
    __syncthreads();
    int dloc = t >> 2, ng = t & 3;
    int d = d0 + dloc;
    f32x4 Alv = *(const f32x4*)&A_log[d*NST + ng*4];
    float An2[4];
#pragma unroll
    for (int j = 0; j < 4; ++j) An2[j] = -__expf(Alv[j]) * LOG2E;
    float h[4] = {0.f, 0.f, 0.f, 0.f};
    float sumd = 0.f;
#pragma unroll 4
    for (int i = 0; i < CH2; ++i) {
        float delta = s_dl[i][dloc];
        float du = delta * s_u[i][dloc];
        f32x4 Bv = *(const f32x4*)&s_B[i][ng*4];
#pragma unroll
        for (int j = 0; j < 4; ++j)
            h[j] = exp2f(delta*An2[j])*h[j] + du*Bv[j];
        sumd += delta;
    }
    long o = ((long)c*DIN + d)*NST + ng*4;
    f32x4 pv, sv;
#pragma unroll
    for (int j = 0; j < 4; ++j) { pv[j] = exp2f(An2[j]*sumd); sv[j] = h[j]; }
    *(f32x4*)&Pc[o] = pv;
    *(f32x4*)&Sc[o] = sv;
}

// ---------------------------------------------------------------------------
// Chunked scan, mid: exclusive prefix over chunks per (d,n); Hin in place.
__global__ __launch_bounds__(256) void scan_mid(
    float* __restrict__ Pc, const float* __restrict__ Sc)
{
    int idx = blockIdx.x*256 + threadIdx.x;
    if (idx >= DIN*NST) return;
    float h = 0.f;
    for (int c = 0; c < NCH2; ++c) {
        long o = (long)c*DIN*NST + idx;
        float p = Pc[o], s = Sc[o];
        Pc[o] = h;
        h = p*h + s;
    }
}

// ---------------------------------------------------------------------------
// Chunked scan, pass 2: re-run chunk from Hin (delta already softplus'ed).
// Fused y+=D*u and y*=silu(z); writes gated y as bf16 into yg (all-batch).
__global__ __launch_bounds__(256) void scan_pass2(
    const float* __restrict__ u, const float* __restrict__ xz,
    const float* __restrict__ bc, const float* __restrict__ Hin,
    const float* __restrict__ A_log, const float* __restrict__ Dp,
    ushort_t* __restrict__ yg, int dir)
{
    __shared__ float s_u[CH2][DPB];
    __shared__ float s_dl[CH2][DPB];    // delta; y written over it
    __shared__ float s_B[CH2][16];
    __shared__ float s_C[CH2][16];
    int t = threadIdx.x;
    int d0 = (blockIdx.x % (DIN/DPB)) * DPB;
    int c  = blockIdx.x / (DIN/DPB);
    int scol = (t & 15) * 4;
#pragma unroll
    for (int i = 0; i < 4; ++i) {
        int row = (t >> 4) + i*16;
        int tau = c*CH2 + row;
        int p = dir ? (LL-1-tau) : tau;
        *(f32x4*)&s_u[row][scol]  = *(const f32x4*)&u[(long)p*DIN + d0 + scol];
        *(f32x4*)&s_dl[row][scol] = *(const f32x4*)&xz[(long)p*(2*DIN) + d0 + scol];
    }
    {
        int row = t >> 2, col = (t & 3)*4;
        int tau = c*CH2 + row;
        int p = dir ? (LL-1-tau) : tau;
        *(f32x4*)&s_B[row][col] = *(const f32x4*)&bc[(long)p*NBC + col];
        *(f32x4*)&s_C[row][col] = *(const f32x4*)&bc[(long)p*NBC + NST + col];
    }
    __syncthreads();
    int dloc = t >> 2, ng = t & 3;
    int d = d0 + dloc;
    f32x4 Alv = *(const f32x4*)&A_log[d*NST + ng*4];
    float An2[4];
#pragma unroll
    for (int j = 0; j < 4; ++j) An2[j] = -__expf(Alv[j]) * LOG2E;
    float Dv = Dp[d];
    f32x4 hv = *(const f32x4*)&Hin[((long)c*DIN + d)*NST + ng*4];
    float h[4] = {hv[0], hv[1], hv[2], hv[3]};
#pragma unroll 4
    for (int i = 0; i < CH2; ++i) {
        float delta = s_dl[i][dloc];
        float uv    = s_u[i][dloc];
        float du    = delta * uv;
        f32x4 Bv = *(const f32x4*)&s_B[i][ng*4];
        f32x4 Cv = *(const f32x4*)&s_C[i][ng*4];
        float prod = 0.f;
#pragma unroll
        for (int j = 0; j < 4; ++j) {
            h[j] = exp2f(delta*An2[j])*h[j] + du*Bv[j];
            prod += h[j]*Cv[j];
        }
        prod += __shfl_xor(prod, 1);
        prod += __shfl_xor(prod, 2);
        if (ng == 0) s_dl[i][dloc] = prod + Dv*uv;   // y over dead delta slot
    }
    __syncthreads();
    // gate phase: y *= silu(z), write bf16, coalesced
#pragma unroll
    for (int i = 0; i < 4; ++i) {
        int row = (t >> 4) + i*16;
        int tau = c*CH2 + row;
        int p = dir ? (LL-1-tau) : tau;
        f32x4 z4 = *(const f32x4*)&xz[(long)p*(2*DIN) + DIN + d0 + scol];
        u16x4 o;
#pragma unroll
        for (int e = 0; e < 4; ++e) {
            float y = s_dl[row][scol + e];
            float z = z4[e];
            o[e] = f2bf(y * z / (1.f + __expf(-z)));
        }
        *(u16x4*)&yg[(long)p*DIN + d0 + scol] = o;
    }
}

// ---------------------------------------------------------------------------
extern "C" void kernel_launch(void* const* d_in, const int* in_sizes, int n_in,
                              void* d_out, int out_size, void* d_ws, size_t ws_size,
                              hipStream_t stream)
{
    const float* x        = (const float*)d_in[0];
    const float* in_w     = (const float*)d_in[1];
    const float* conv_w   = (const float*)d_in[2];
    const float* conv_b   = (const float*)d_in[3];
    const float* xproj_w  = (const float*)d_in[4];
    const float* dt_w     = (const float*)d_in[5];
    const float* dt_b     = (const float*)d_in[6];
    const float* A_log    = (const float*)d_in[7];
    const float* Dp       = (const float*)d_in[8];
    const float* out_w    = (const float*)d_in[9];
    const float* ln_g     = (const float*)d_in[10];
    const float* ln_b     = (const float*)d_in[11];
    const float* fus_w    = (const float*)d_in[12];
    const float* fus_b    = (const float*)d_in[13];
    float* out = (float*)d_out;

    // workspace layout, ~110 MB total. f32 buffers first, then bf16.
    float* ws   = (float*)d_ws;
    float* xzc  = ws;                        // 2048*3072 = 6,291,456 f32 (per-b)
    float* uc   = xzc + (long)LL*2*DIN;      // 2048*1536 = 3,145,728 (per-b)
    float* bcb  = uc  + (long)LL*DIN;        // 2048*32   =    65,536 (per-b)
    float* Pc   = bcb + (long)LL*NBC;        // 32*1536*16=   786,432
    float* Sc   = Pc  + (long)NCH2*DIN*NST;  // 32*1536*16=   786,432
    ushort_t* xn_bf  = (ushort_t*)(Sc + (long)NCH2*DIN*NST); // 2048*768 (per-b)
    ushort_t* u_bf   = xn_bf  + (long)LL*DD;        // 2048*1536 (per-b)
    ushort_t* yg_all = u_bf   + (long)LL*DIN;       // 8192*1536 (ALL batches)
    ushort_t* in_w_bf= yg_all + (long)BB*LL*DIN;    // 2*3072*768
    ushort_t* wdc_bf = in_w_bf+ 2L*2*DIN*DD;        // 2*1568*1536
    ushort_t* wc_bf  = wdc_bf + 2L*NCOMB*DIN;       // 2*768*1536
    ushort_t* owt_bf = wc_bf  + 2L*DD*DIN;          // 2*1536*768
    ushort_t* fus_bf = owt_bf + 2L*DIN*DD;          // 768*1536

    // ---- weight prep (per call, batch-independent) ----
    cvt_bf16<<<(DD*2*DD)/256, 256, 0, stream>>>(fus_w, fus_bf, (long)DD*2*DD);
    for (int dir = 0; dir < 2; ++dir) {
        cvt_bf16<<<(2*DIN*DD)/256, 256, 0, stream>>>(
            in_w + (long)dir*2*DIN*DD, in_w_bf + (long)dir*2*DIN*DD,
            (long)2*DIN*DD);
        wdcat_build<<<(NCOMB*DIN)/256, 256, 0, stream>>>(
            dt_w + (long)dir*DIN*RR, xproj_w + (long)dir*(RR+2*NST)*DIN,
            wdc_bf + (long)dir*NCOMB*DIN);
        owt_cvt<<<(DIN*DD)/256, 256, 0, stream>>>(
            out_w + (long)dir*DD*DIN, owt_bf + (long)dir*DIN*DD);
        // Wc[dir] = fus_w[:, dir*768:+768] @ out_w[dir]  (768 x 1536, K=768)
        gemm_mfma<<<dim3(12,6), 256, 0, stream>>>(
            fus_bf + dir*DD, owt_bf + (long)dir*DIN*DD, nullptr, nullptr,
            xzc, nullptr, DD, DIN, DD, 2*DD, DIN, 0, DIN, 0);
        cvt_bf16<<<(DD*DIN)/256, 256, 0, stream>>>(
            xzc, wc_bf + (long)dir*DD*DIN, (long)DD*DIN);
    }

    for (int dir = 0; dir < 2; ++dir) {
        for (int b = 0; b < BB; ++b) {
            const float* xb = x + (long)b*LL*DD;
            ln_kernel<<<LL, 256, 0, stream>>>(xb, ln_g, ln_b, xn_bf);
            // xz = xn @ in_w[dir].T   (2048 x 3072, K=768)
            gemm_mfma<<<dim3(24,16), 256, 0, stream>>>(
                xn_bf, in_w_bf + (long)dir*2*DIN*DD, nullptr, nullptr,
                xzc, nullptr, LL, 2*DIN, DD, DD, 2*DIN, 0, 2*DIN, 0);
            // u = silu(conv(xc) + cb)  -> f32 + bf16
            conv_silu<<<(LL*DIN/4)/256, 256, 0, stream>>>(
                xzc, conv_w + dir*DIN*CD, conv_b + dir*DIN, uc, u_bf, dir);
            // [delta_pre | B | C] = u @ Wcomb.T  (2048 x 1568, K=1536)
            gemm_mfma<<<dim3(13,16), 256, 0, stream>>>(
                u_bf, wdc_bf + (long)dir*NCOMB*DIN, dt_b + dir*DIN, nullptr,
                xzc, bcb, LL, NCOMB, DIN, DIN, 2*DIN, 0, DIN, NBC);
            // chunked selective scan -> yg_all[b]
            scan_pass1<<<(DIN/DPB)*NCH2, 256, 0, stream>>>(
                uc, xzc, bcb, A_log + (long)dir*DIN*NST, Pc, Sc, dir);
            scan_mid<<<(DIN*NST)/256, 256, 0, stream>>>(Pc, Sc);
            scan_pass2<<<(DIN/DPB)*NCH2, 256, 0, stream>>>(
                uc, xzc, bcb, Pc, A_log + (long)dir*DIN*NST, Dp + dir*DIN,
                yg_all + (long)b*LL*DIN, dir);
        }
        // merged out-GEMM over all batches: M=8192
        if (dir == 0) {
            gemm_mfma<<<dim3(6,64), 256, 0, stream>>>(
                yg_all, wc_bf, fus_b, x,
                out, nullptr, BB*LL, DD, DIN, DIN, DD, DD, DD, 0);
        } else {
            gemm_mfma<<<dim3(6,64), 256, 0, stream>>>(
                yg_all, wc_bf + (long)DD*DIN, nullptr, out,
                out, nullptr, BB*LL, DD, DIN, DIN, DD, DD, DD, 0);
        }
    }
}

// Round 8
// 1316.877 us; speedup vs baseline: 8.1186x; 1.0441x over previous
//
#include <hip/hip_runtime.h>
#include <hip/hip_bf16.h>

// Problem constants
#define BB 4
#define LL 2048
#define DD 768
#define DIN 1536
#define NST 16
#define CD 4
#define RR 48
#define NBC 32          // B,C columns (2*NST)
#define NCOMB (DIN+NBC) // 1568: combined [delta | B | C] GEMM width
#define CH2 64          // scan chunk length
#define NCH2 (LL/CH2)   // 32 chunks
#define DPB 64          // d-channels per scan block
#define LOG2E 1.44269504088896f

typedef unsigned short ushort_t;
typedef unsigned int u32;
typedef __attribute__((ext_vector_type(4))) float f32x4;
typedef __attribute__((ext_vector_type(8))) short bf16x8;
typedef __attribute__((ext_vector_type(4))) ushort_t u16x4;

static __device__ __forceinline__ ushort_t f2bf(float f) {
    unsigned int u = __float_as_uint(f);
    u += 0x7FFF + ((u >> 16) & 1);          // RNE
    return (ushort_t)(u >> 16);
}
static __device__ __forceinline__ float bf2f(ushort_t h) {
    return __uint_as_float(((u32)h) << 16);
}

static __device__ __forceinline__ void gload_lds16(const void* g, void* l) {
    __builtin_amdgcn_global_load_lds(
        (const __attribute__((address_space(1))) u32*)g,
        (__attribute__((address_space(3))) u32*)l, 16, 0, 0);
}

// ---------------------------------------------------------------------------
// LayerNorm over last dim (768). One block (256 thr) per row, ALL batches.
__global__ __launch_bounds__(256) void ln_kernel(
    const float* __restrict__ x, const float* __restrict__ g,
    const float* __restrict__ b, ushort_t* __restrict__ xn)
{
    int row = blockIdx.x;
    const float* xr = x + (long)row * DD;
    int t = threadIdx.x;
    float v[3];
    float s = 0.f;
#pragma unroll
    for (int i = 0; i < 3; ++i) { v[i] = xr[t + i*256]; s += v[i]; }
#pragma unroll
    for (int off = 32; off >= 1; off >>= 1) s += __shfl_xor(s, off);
    __shared__ float red[4], red2[4];
    int wid = t >> 6;
    if ((t & 63) == 0) red[wid] = s;
    __syncthreads();
    float mean = (red[0]+red[1]+red[2]+red[3]) * (1.f/768.f);
    float vs = 0.f;
#pragma unroll
    for (int i = 0; i < 3; ++i) { float d0 = v[i]-mean; vs += d0*d0; }
#pragma unroll
    for (int off = 32; off >= 1; off >>= 1) vs += __shfl_xor(vs, off);
    if ((t & 63) == 0) red2[wid] = vs;
    __syncthreads();
    float var = (red2[0]+red2[1]+red2[2]+red2[3]) * (1.f/768.f);
    float rstd = rsqrtf(var + 1e-5f);
    ushort_t* xo = xn + (long)row * DD;
#pragma unroll
    for (int i = 0; i < 3; ++i) {
        int c = t + i*256;
        xo[c] = f2bf((v[i]-mean)*rstd*g[c] + b[c]);
    }
}

// ---------------------------------------------------------------------------
// elementwise f32 -> bf16 convert
__global__ __launch_bounds__(256) void cvt_bf16(
    const float* __restrict__ in, ushort_t* __restrict__ out, long n)
{
    long i = (long)blockIdx.x*256 + threadIdx.x;
    if (i < n) out[i] = f2bf(in[i]);
}

// ---------------------------------------------------------------------------
// transpose-convert out_w (DD x DIN, row-major) -> owt (DIN x DD) bf16
__global__ __launch_bounds__(256) void owt_cvt(
    const float* __restrict__ ow, ushort_t* __restrict__ out)
{
    long idx = (long)blockIdx.x*256 + threadIdx.x;
    if (idx >= (long)DIN*DD) return;
    int k = (int)(idx % DD);   // source row
    int n = (int)(idx / DD);   // source col
    out[idx] = f2bf(ow[(long)k*DIN + n]);
}

// ---------------------------------------------------------------------------
// Build combined [Wdc | xw_B | xw_C] bf16 weight (NCOMB x DIN)
__global__ __launch_bounds__(256) void wdcat_build(
    const float* __restrict__ dt_w, const float* __restrict__ xw,
    ushort_t* __restrict__ out)
{
    long idx = (long)blockIdx.x*256 + threadIdx.x;
    if (idx >= (long)NCOMB*DIN) return;
    int k = (int)(idx % DIN);
    int d = (int)(idx / DIN);
    float acc;
    if (d < DIN) {
        acc = 0.f;
#pragma unroll 8
        for (int r = 0; r < RR; ++r)
            acc += dt_w[d*RR + r] * xw[(long)r*DIN + k];
    } else {
        acc = xw[(long)(RR + d - DIN)*DIN + k];
    }
    out[idx] = f2bf(acc);
}

// ---------------------------------------------------------------------------
// MFMA GEMM, bf16 x bf16 -> f32 acc. Double-buffered LDS, one barrier/K-step.
// XCD-aware swizzle: grid size MUST be a multiple of 8.
// Epilogue variants:
//  EPI=0: C f32 (+bias +resid), C2 f32
//  EPI=1: C bf16 (plain),       C2 bf16
//  EPI=2: C bf16 softplus(v+bias), C2 f32   (comb GEMM: delta | B,C)
template<int EPI>
__global__ __launch_bounds__(256) void gemm_mfma(
    const ushort_t* __restrict__ A, const ushort_t* __restrict__ Wb,
    const float* __restrict__ bias, const float* __restrict__ resid,
    void* __restrict__ Cv, void* __restrict__ C2v,
    int M, int N, int K, int lda, int ldc, int ldr, int n_split, int ldc2)
{
    __shared__ __attribute__((aligned(16))) ushort_t As[2][128*32];
    __shared__ __attribute__((aligned(16))) ushort_t Bs[2][128*32];
    int tid = threadIdx.x;
    // XCD swizzle: consecutive logical tiles -> same XCD (bijective, nwg%8==0)
    int gx = gridDim.x;
    int nwg = gx * gridDim.y;
    int flat = blockIdx.y * gx + blockIdx.x;
    int L = (flat & 7) * (nwg >> 3) + (flat >> 3);
    int bm = (L / gx) * 128, bn = (L % gx) * 128;
    int lane = tid & 63, w = tid >> 6;
    int wr = w >> 1, wc = w & 1;
    int lrow = lane & 15, kg = lane >> 4;
    int srowA = lane >> 2;          // 0..15 within chunk
    int sc8  = lane & 3;            // 16B slot within 64B row

    auto stage = [&](int buf, int kk) {
#pragma unroll
        for (int it = 0; it < 2; ++it) {
            int chunk = it*4 + w;                  // 0..7 (wave-uniform)
            int row = chunk*16 + srowA;            // 0..127
            gload_lds16(&A[(long)(bm+row)*lda + kk + sc8*8],
                        &As[buf][chunk*512]);
        }
#pragma unroll
        for (int it = 0; it < 2; ++it) {
            int chunk = it*4 + w;
            int row = chunk*16 + srowA;
            int n = bn + row; if (n > N-1) n = N-1;
            gload_lds16(&Wb[(long)n*K + kk + sc8*8],
                        &Bs[buf][chunk*512]);
        }
    };

    f32x4 acc[4][4] = {};
    int nt = K >> 5;
    stage(0, 0);                    // prologue

    for (int t = 0; t < nt; ++t) {
        int cur = t & 1;
        __syncthreads();            // vmcnt(0)+barrier: buf[cur] staged
        if (t + 1 < nt) stage(cur ^ 1, (t + 1) << 5);
        bf16x8 af[4], bfv[4];
#pragma unroll
        for (int mi = 0; mi < 4; ++mi)
            af[mi] = *(const bf16x8*)&As[cur][(wr*64 + mi*16 + lrow)*32 + kg*8];
#pragma unroll
        for (int ni = 0; ni < 4; ++ni)
            bfv[ni] = *(const bf16x8*)&Bs[cur][(wc*64 + ni*16 + lrow)*32 + kg*8];
#pragma unroll
        for (int mi = 0; mi < 4; ++mi)
#pragma unroll
            for (int ni = 0; ni < 4; ++ni)
                acc[mi][ni] = __builtin_amdgcn_mfma_f32_16x16x32_bf16(
                    af[mi], bfv[ni], acc[mi][ni], 0, 0, 0);
    }

    // epilogue: C/D frag mapping col=lane&15, row=(lane>>4)*4+reg
#pragma unroll
    for (int mi = 0; mi < 4; ++mi) {
#pragma unroll
        for (int ni = 0; ni < 4; ++ni) {
            int n = bn + wc*64 + ni*16 + lrow;
            if (n >= N) continue;
#pragma unroll
            for (int reg = 0; reg < 4; ++reg) {
                int m = bm + wr*64 + mi*16 + kg*4 + reg;
                float v = acc[mi][ni][reg];
                if (EPI == 0) {
                    if (n < n_split) {
                        if (bias)  v += bias[n];
                        if (resid) v += resid[(long)m*ldr + n];
                        ((float*)Cv)[(long)m*ldc + n] = v;
                    } else {
                        ((float*)C2v)[(long)m*ldc2 + (n - n_split)] = v;
                    }
                } else if (EPI == 1) {
                    if (n < n_split)
                        ((ushort_t*)Cv)[(long)m*ldc + n] = f2bf(v);
                    else
                        ((ushort_t*)C2v)[(long)m*ldc2 + (n - n_split)] = f2bf(v);
                } else {
                    if (n < n_split) {
                        v += bias[n];
                        float sp = (v > 20.f) ? v : log1pf(__expf(v));
                        ((ushort_t*)Cv)[(long)m*ldc + n] = f2bf(sp);
                    } else {
                        ((float*)C2v)[(long)m*ldc2 + (n - n_split)] = v;
                    }
                }
            }
        }
    }
}

// ---------------------------------------------------------------------------
// Depthwise causal/anti-causal conv + bias + SiLU. bf16 in (xc), bf16 out (u).
__global__ __launch_bounds__(256) void conv_silu(
    const ushort_t* __restrict__ xc, const float* __restrict__ cw,
    const float* __restrict__ cb, ushort_t* __restrict__ ub, int dir)
{
    long idx4 = (long)blockIdx.x * 256 + threadIdx.x;   // LL*DIN/4 total
    int dq = (int)(idx4 % (DIN/4));
    int l  = (int)(idx4 / (DIN/4));
    int d  = dq * 4;
    f32x4 acc = *(const f32x4*)&cb[d];
    f32x4 w0 = *(const f32x4*)&cw[(d+0)*CD];
    f32x4 w1 = *(const f32x4*)&cw[(d+1)*CD];
    f32x4 w2 = *(const f32x4*)&cw[(d+2)*CD];
    f32x4 w3 = *(const f32x4*)&cw[(d+3)*CD];
#pragma unroll
    for (int k = 0; k < CD; ++k) {
        int j = dir ? (l + 3 - k) : (l - 3 + k);
        if (j >= 0 && j < LL) {
            u16x4 xv = *(const u16x4*)&xc[(long)j*DIN + d];
            acc[0] += w0[k]*bf2f(xv[0]);
            acc[1] += w1[k]*bf2f(xv[1]);
            acc[2] += w2[k]*bf2f(xv[2]);
            acc[3] += w3[k]*bf2f(xv[3]);
        }
    }
    u16x4 o;
#pragma unroll
    for (int e = 0; e < 4; ++e)
        o[e] = f2bf(acc[e] / (1.f + __expf(-acc[e])));   // silu
    *(u16x4*)&ub[idx4*4] = o;
}

// ---------------------------------------------------------------------------
// Chunked selective scan, pass 1. Block = 256 thr = 64 d x 4 n-groups
// (4 states/thread). delta is ALREADY softplus'ed bf16 (comb GEMM epilogue).
__global__ __launch_bounds__(256) void scan_pass1(
    const ushort_t* __restrict__ u, const ushort_t* __restrict__ dl,
    const float* __restrict__ bc, const float* __restrict__ A_log,
    float* __restrict__ Pc, float* __restrict__ Sc, int dir)
{
    __shared__ float s_u[CH2][DPB];
    __shared__ float s_dl[CH2][DPB];
    __shared__ float s_B[CH2][16];
    int t = threadIdx.x;
    int d0 = (blockIdx.x % (DIN/DPB)) * DPB;
    int c  = blockIdx.x / (DIN/DPB);
    int scol = (t & 15) * 4;
#pragma unroll
    for (int i = 0; i < 4; ++i) {
        int row = (t >> 4) + i*16;
        int tau = c*CH2 + row;
        int p = dir ? (LL-1-tau) : tau;
        u16x4 uv = *(const u16x4*)&u[(long)p*DIN + d0 + scol];
        u16x4 dv = *(const u16x4*)&dl[(long)p*DIN + d0 + scol];
        f32x4 uf, df;
#pragma unroll
        for (int e = 0; e < 4; ++e) { uf[e] = bf2f(uv[e]); df[e] = bf2f(dv[e]); }
        *(f32x4*)&s_u[row][scol] = uf;
        *(f32x4*)&s_dl[row][scol] = df;
    }
    {
        int row = t >> 2, col = (t & 3)*4;
        int tau = c*CH2 + row;
        int p = dir ? (LL-1-tau) : tau;
        *(f32x4*)&s_B[row][col] = *(const f32x4*)&bc[(long)p*NBC + col];
    }
    __syncthreads();
    int dloc = t >> 2, ng = t & 3;
    int d = d0 + dloc;
    f32x4 Alv = *(const f32x4*)&A_log[d*NST + ng*4];
    float An2[4];
#pragma unroll
    for (int j = 0; j < 4; ++j) An2[j] = -__expf(Alv[j]) * LOG2E;
    float h[4] = {0.f, 0.f, 0.f, 0.f};
    float sumd = 0.f;
#pragma unroll 4
    for (int i = 0; i < CH2; ++i) {
        float delta = s_dl[i][dloc];
        float du = delta * s_u[i][dloc];
        f32x4 Bv = *(const f32x4*)&s_B[i][ng*4];
#pragma unroll
        for (int j = 0; j < 4; ++j)
            h[j] = exp2f(delta*An2[j])*h[j] + du*Bv[j];
        sumd += delta;
    }
    long o = ((long)c*DIN + d)*NST + ng*4;
    f32x4 pv, sv;
#pragma unroll
    for (int j = 0; j < 4; ++j) { pv[j] = exp2f(An2[j]*sumd); sv[j] = h[j]; }
    *(f32x4*)&Pc[o] = pv;
    *(f32x4*)&Sc[o] = sv;
}

// ---------------------------------------------------------------------------
// Chunked scan, mid: exclusive prefix over chunks per (d,n); Hin in place.
__global__ __launch_bounds__(256) void scan_mid(
    float* __restrict__ Pc, const float* __restrict__ Sc)
{
    int idx = blockIdx.x*256 + threadIdx.x;
    if (idx >= DIN*NST) return;
    float h = 0.f;
    for (int c = 0; c < NCH2; ++c) {
        long o = (long)c*DIN*NST + idx;
        float p = Pc[o], s = Sc[o];
        Pc[o] = h;
        h = p*h + s;
    }
}

// ---------------------------------------------------------------------------
// Chunked scan, pass 2: re-run chunk from Hin; fused y+=D*u, y*=silu(z);
// writes gated y bf16 into yg (all-batch buffer).
__global__ __launch_bounds__(256) void scan_pass2(
    const ushort_t* __restrict__ u, const ushort_t* __restrict__ dl,
    const ushort_t* __restrict__ zb, const float* __restrict__ bc,
    const float* __restrict__ Hin,
    const float* __restrict__ A_log, const float* __restrict__ Dp,
    ushort_t* __restrict__ yg, int dir)
{
    __shared__ float s_u[CH2][DPB];
    __shared__ float s_dl[CH2][DPB];    // delta; y written over it
    __shared__ float s_B[CH2][16];
    __shared__ float s_C[CH2][16];
    int t = threadIdx.x;
    int d0 = (blockIdx.x % (DIN/DPB)) * DPB;
    int c  = blockIdx.x / (DIN/DPB);
    int scol = (t & 15) * 4;
#pragma unroll
    for (int i = 0; i < 4; ++i) {
        int row = (t >> 4) + i*16;
        int tau = c*CH2 + row;
        int p = dir ? (LL-1-tau) : tau;
        u16x4 uv = *(const u16x4*)&u[(long)p*DIN + d0 + scol];
        u16x4 dv = *(const u16x4*)&dl[(long)p*DIN + d0 + scol];
        f32x4 uf, df;
#pragma unroll
        for (int e = 0; e < 4; ++e) { uf[e] = bf2f(uv[e]); df[e] = bf2f(dv[e]); }
        *(f32x4*)&s_u[row][scol] = uf;
        *(f32x4*)&s_dl[row][scol] = df;
    }
    {
        int row = t >> 2, col = (t & 3)*4;
        int tau = c*CH2 + row;
        int p = dir ? (LL-1-tau) : tau;
        *(f32x4*)&s_B[row][col] = *(const f32x4*)&bc[(long)p*NBC + col];
        *(f32x4*)&s_C[row][col] = *(const f32x4*)&bc[(long)p*NBC + NST + col];
    }
    __syncthreads();
    int dloc = t >> 2, ng = t & 3;
    int d = d0 + dloc;
    f32x4 Alv = *(const f32x4*)&A_log[d*NST + ng*4];
    float An2[4];
#pragma unroll
    for (int j = 0; j < 4; ++j) An2[j] = -__expf(Alv[j]) * LOG2E;
    float Dv = Dp[d];
    f32x4 hv = *(const f32x4*)&Hin[((long)c*DIN + d)*NST + ng*4];
    float h[4] = {hv[0], hv[1], hv[2], hv[3]};
#pragma unroll 4
    for (int i = 0; i < CH2; ++i) {
        float delta = s_dl[i][dloc];
        float uv    = s_u[i][dloc];
        float du    = delta * uv;
        f32x4 Bv = *(const f32x4*)&s_B[i][ng*4];
        f32x4 Cv = *(const f32x4*)&s_C[i][ng*4];
        float prod = 0.f;
#pragma unroll
        for (int j = 0; j < 4; ++j) {
            h[j] = exp2f(delta*An2[j])*h[j] + du*Bv[j];
            prod += h[j]*Cv[j];
        }
        prod += __shfl_xor(prod, 1);
        prod += __shfl_xor(prod, 2);
        if (ng == 0) s_dl[i][dloc] = prod + Dv*uv;   // y over dead delta slot
    }
    __syncthreads();
    // gate phase: y *= silu(z), write bf16, coalesced
#pragma unroll
    for (int i = 0; i < 4; ++i) {
        int row = (t >> 4) + i*16;
        int tau = c*CH2 + row;
        int p = dir ? (LL-1-tau) : tau;
        u16x4 z4 = *(const u16x4*)&zb[(long)p*DIN + d0 + scol];
        u16x4 o;
#pragma unroll
        for (int e = 0; e < 4; ++e) {
            float y = s_dl[row][scol + e];
            float z = bf2f(z4[e]);
            o[e] = f2bf(y * z / (1.f + __expf(-z)));
        }
        *(u16x4*)&yg[(long)p*DIN + d0 + scol] = o;
    }
}

// ---------------------------------------------------------------------------
extern "C" void kernel_launch(void* const* d_in, const int* in_sizes, int n_in,
                              void* d_out, int out_size, void* d_ws, size_t ws_size,
                              hipStream_t stream)
{
    const float* x        = (const float*)d_in[0];
    const float* in_w     = (const float*)d_in[1];
    const float* conv_w   = (const float*)d_in[2];
    const float* conv_b   = (const float*)d_in[3];
    const float* xproj_w  = (const float*)d_in[4];
    const float* dt_w     = (const float*)d_in[5];
    const float* dt_b     = (const float*)d_in[6];
    const float* A_log    = (const float*)d_in[7];
    const float* Dp       = (const float*)d_in[8];
    const float* out_w    = (const float*)d_in[9];
    const float* ln_g     = (const float*)d_in[10];
    const float* ln_b     = (const float*)d_in[11];
    const float* fus_w    = (const float*)d_in[12];
    const float* fus_b    = (const float*)d_in[13];
    float* out = (float*)d_out;

    // workspace layout, ~100 MB. f32 first, then bf16.
    float* ws   = (float*)d_ws;
    float* bcb  = ws;                        // 2048*32      =    65,536 f32
    float* Pc   = bcb + (long)LL*NBC;        // 32*1536*16   =   786,432
    float* Sc   = Pc  + (long)NCH2*DIN*NST;  // 32*1536*16   =   786,432
    ushort_t* xn_all = (ushort_t*)(Sc + (long)NCH2*DIN*NST); // 8192*768
    ushort_t* xc_bf  = xn_all + (long)BB*LL*DD;   // 2048*1536 (per b,dir)
    ushort_t* z_bf   = xc_bf  + (long)LL*DIN;     // 2048*1536
    ushort_t* u_bf   = z_bf   + (long)LL*DIN;     // 2048*1536
    ushort_t* dl_bf  = u_bf   + (long)LL*DIN;     // 2048*1536
    ushort_t* yg_all = dl_bf  + (long)LL*DIN;     // 8192*1536 (ALL batches)
    ushort_t* in_w_bf= yg_all + (long)BB*LL*DIN;  // 2*3072*768
    ushort_t* wdc_bf = in_w_bf+ 2L*2*DIN*DD;      // 2*1568*1536
    ushort_t* wc_bf  = wdc_bf + 2L*NCOMB*DIN;     // 2*768*1536
    ushort_t* owt_bf = wc_bf  + 2L*DD*DIN;        // 2*1536*768
    ushort_t* fus_bf = owt_bf + 2L*DIN*DD;        // 768*1536

    // ---- weight prep (per call, batch-independent) ----
    cvt_bf16<<<(DD*2*DD)/256, 256, 0, stream>>>(fus_w, fus_bf, (long)DD*2*DD);
    for (int dir = 0; dir < 2; ++dir) {
        cvt_bf16<<<(2*DIN*DD)/256, 256, 0, stream>>>(
            in_w + (long)dir*2*DIN*DD, in_w_bf + (long)dir*2*DIN*DD,
            (long)2*DIN*DD);
        wdcat_build<<<(NCOMB*DIN)/256, 256, 0, stream>>>(
            dt_w + (long)dir*DIN*RR, xproj_w + (long)dir*(RR+2*NST)*DIN,
            wdc_bf + (long)dir*NCOMB*DIN);
        owt_cvt<<<(DIN*DD)/256, 256, 0, stream>>>(
            out_w + (long)dir*DD*DIN, owt_bf + (long)dir*DIN*DD);
        // Wc[dir] = fus_w[:, dir*768:+768] @ out_w[dir]  -> bf16 directly
        gemm_mfma<1><<<dim3(12,6), 256, 0, stream>>>(
            fus_bf + dir*DD, owt_bf + (long)dir*DIN*DD, nullptr, nullptr,
            wc_bf + (long)dir*DD*DIN, nullptr,
            DD, DIN, DD, 2*DD, DIN, 0, DIN, 0);
    }

    // LN once for all batches
    ln_kernel<<<BB*LL, 256, 0, stream>>>(x, ln_g, ln_b, xn_all);

    for (int dir = 0; dir < 2; ++dir) {
        for (int b = 0; b < BB; ++b) {
            // [xc | z] = xn @ in_w[dir].T   (2048 x 3072, K=768) -> bf16 split
            gemm_mfma<1><<<dim3(24,16), 256, 0, stream>>>(
                xn_all + (long)b*LL*DD, in_w_bf + (long)dir*2*DIN*DD,
                nullptr, nullptr, xc_bf, z_bf,
                LL, 2*DIN, DD, DD, DIN, 0, DIN, DIN);
            // u = silu(conv(xc) + cb)  -> bf16
            conv_silu<<<(LL*DIN/4)/256, 256, 0, stream>>>(
                xc_bf, conv_w + dir*DIN*CD, conv_b + dir*DIN, u_bf, dir);
            // [softplus(delta+dt_b) | B | C] = u @ Wcomb.T  (2048x1568, K=1536)
            gemm_mfma<2><<<dim3(13,16), 256, 0, stream>>>(
                u_bf, wdc_bf + (long)dir*NCOMB*DIN, dt_b + dir*DIN, nullptr,
                dl_bf, bcb, LL, NCOMB, DIN, DIN, DIN, 0, DIN, NBC);
            // chunked selective scan -> yg_all[b]
            scan_pass1<<<(DIN/DPB)*NCH2, 256, 0, stream>>>(
                u_bf, dl_bf, bcb, A_log + (long)dir*DIN*NST, Pc, Sc, dir);
            scan_mid<<<(DIN*NST)/256, 256, 0, stream>>>(Pc, Sc);
            scan_pass2<<<(DIN/DPB)*NCH2, 256, 0, stream>>>(
                u_bf, dl_bf, z_bf, bcb, Pc, A_log + (long)dir*DIN*NST,
                Dp + dir*DIN, yg_all + (long)b*LL*DIN, dir);
        }
        // merged out-GEMM over all batches: M=8192
        if (dir == 0) {
            gemm_mfma<0><<<dim3(6,64), 256, 0, stream>>>(
                yg_all, wc_bf, fus_b, x,
                out, nullptr, BB*LL, DD, DIN, DIN, DD, DD, DD, 0);
        } else {
            gemm_mfma<0><<<dim3(6,64), 256, 0, stream>>>(
                yg_all, wc_bf + (long)DD*DIN, nullptr, out,
                out, nullptr, BB*LL, DD, DIN, DIN, DD, DD, DD, 0);
        }
    }
}

// Round 9
// 1011.796 us; speedup vs baseline: 10.5665x; 1.3015x over previous
//
#include <hip/hip_runtime.h>
#include <hip/hip_bf16.h>

// Problem constants
#define BB 4
#define LL 2048
#define DD 768
#define DIN 1536
#define NST 16
#define CD 4
#define RR 48
#define NBC 32          // B,C columns (2*NST)
#define NCOMB (DIN+NBC) // 1568: combined [delta | B | C] GEMM width
#define CH2 64          // scan chunk length
#define NCH2 (LL/CH2)   // 32 chunks
#define DPB 64          // d-channels per scan block
#define LOG2E 1.44269504088896f

typedef unsigned short ushort_t;
typedef unsigned int u32;
typedef __attribute__((ext_vector_type(4))) float f32x4;
typedef __attribute__((ext_vector_type(8))) short bf16x8;
typedef __attribute__((ext_vector_type(4))) ushort_t u16x4;

static __device__ __forceinline__ ushort_t f2bf(float f) {
    unsigned int u = __float_as_uint(f);
    u += 0x7FFF + ((u >> 16) & 1);          // RNE
    return (ushort_t)(u >> 16);
}
static __device__ __forceinline__ float bf2f(ushort_t h) {
    return __uint_as_float(((u32)h) << 16);
}

static __device__ __forceinline__ void gload_lds16(const void* g, void* l) {
    __builtin_amdgcn_global_load_lds(
        (const __attribute__((address_space(1))) u32*)g,
        (__attribute__((address_space(3))) u32*)l, 16, 0, 0);
}

// ---------------------------------------------------------------------------
// LayerNorm over last dim (768). One block (256 thr) per row, ALL batches.
__global__ __launch_bounds__(256) void ln_kernel(
    const float* __restrict__ x, const float* __restrict__ g,
    const float* __restrict__ b, ushort_t* __restrict__ xn)
{
    int row = blockIdx.x;
    const float* xr = x + (long)row * DD;
    int t = threadIdx.x;
    float v[3];
    float s = 0.f;
#pragma unroll
    for (int i = 0; i < 3; ++i) { v[i] = xr[t + i*256]; s += v[i]; }
#pragma unroll
    for (int off = 32; off >= 1; off >>= 1) s += __shfl_xor(s, off);
    __shared__ float red[4], red2[4];
    int wid = t >> 6;
    if ((t & 63) == 0) red[wid] = s;
    __syncthreads();
    float mean = (red[0]+red[1]+red[2]+red[3]) * (1.f/768.f);
    float vs = 0.f;
#pragma unroll
    for (int i = 0; i < 3; ++i) { float d0 = v[i]-mean; vs += d0*d0; }
#pragma unroll
    for (int off = 32; off >= 1; off >>= 1) vs += __shfl_xor(vs, off);
    if ((t & 63) == 0) red2[wid] = vs;
    __syncthreads();
    float var = (red2[0]+red2[1]+red2[2]+red2[3]) * (1.f/768.f);
    float rstd = rsqrtf(var + 1e-5f);
    ushort_t* xo = xn + (long)row * DD;
#pragma unroll
    for (int i = 0; i < 3; ++i) {
        int c = t + i*256;
        xo[c] = f2bf((v[i]-mean)*rstd*g[c] + b[c]);
    }
}

// ---------------------------------------------------------------------------
// elementwise f32 -> bf16 convert
__global__ __launch_bounds__(256) void cvt_bf16(
    const float* __restrict__ in, ushort_t* __restrict__ out, long n)
{
    long i = (long)blockIdx.x*256 + threadIdx.x;
    if (i < n) out[i] = f2bf(in[i]);
}

// ---------------------------------------------------------------------------
// transpose-convert out_w (DD x DIN, row-major) -> owt (DIN x DD) bf16
__global__ __launch_bounds__(256) void owt_cvt(
    const float* __restrict__ ow, ushort_t* __restrict__ out)
{
    long idx = (long)blockIdx.x*256 + threadIdx.x;
    if (idx >= (long)DIN*DD) return;
    int k = (int)(idx % DD);   // source row
    int n = (int)(idx / DD);   // source col
    out[idx] = f2bf(ow[(long)k*DIN + n]);
}

// ---------------------------------------------------------------------------
// Build combined [Wdc | xw_B | xw_C] bf16 weight (NCOMB x DIN)
__global__ __launch_bounds__(256) void wdcat_build(
    const float* __restrict__ dt_w, const float* __restrict__ xw,
    ushort_t* __restrict__ out)
{
    long idx = (long)blockIdx.x*256 + threadIdx.x;
    if (idx >= (long)NCOMB*DIN) return;
    int k = (int)(idx % DIN);
    int d = (int)(idx / DIN);
    float acc;
    if (d < DIN) {
        acc = 0.f;
#pragma unroll 8
        for (int r = 0; r < RR; ++r)
            acc += dt_w[d*RR + r] * xw[(long)r*DIN + k];
    } else {
        acc = xw[(long)(RR + d - DIN)*DIN + k];
    }
    out[idx] = f2bf(acc);
}

// ---------------------------------------------------------------------------
// MFMA GEMM, bf16 x bf16 -> f32 acc. Double-buffered LDS, one barrier/K-step.
// XCD-aware swizzle: grid size MUST be a multiple of 8.
// Epilogue variants:
//  EPI=0: C f32 (+bias +resid), C2 f32
//  EPI=1: C bf16 (plain),       C2 bf16
//  EPI=2: C bf16 softplus(v+bias), C2 f32   (comb GEMM: delta | B,C)
template<int EPI>
__global__ __launch_bounds__(256) void gemm_mfma(
    const ushort_t* __restrict__ A, const ushort_t* __restrict__ Wb,
    const float* __restrict__ bias, const float* __restrict__ resid,
    void* __restrict__ Cv, void* __restrict__ C2v,
    int M, int N, int K, int lda, int ldc, int ldr, int n_split, int ldc2)
{
    __shared__ __attribute__((aligned(16))) ushort_t As[2][128*32];
    __shared__ __attribute__((aligned(16))) ushort_t Bs[2][128*32];
    int tid = threadIdx.x;
    // XCD swizzle: consecutive logical tiles -> same XCD (bijective, nwg%8==0)
    int gx = gridDim.x;
    int nwg = gx * gridDim.y;
    int flat = blockIdx.y * gx + blockIdx.x;
    int L = (flat & 7) * (nwg >> 3) + (flat >> 3);
    int bm = (L / gx) * 128, bn = (L % gx) * 128;
    int lane = tid & 63, w = tid >> 6;
    int wr = w >> 1, wc = w & 1;
    int lrow = lane & 15, kg = lane >> 4;
    int srowA = lane >> 2;          // 0..15 within chunk
    int sc8  = lane & 3;            // 16B slot within 64B row

    auto stage = [&](int buf, int kk) {
#pragma unroll
        for (int it = 0; it < 2; ++it) {
            int chunk = it*4 + w;                  // 0..7 (wave-uniform)
            int row = chunk*16 + srowA;            // 0..127
            gload_lds16(&A[(long)(bm+row)*lda + kk + sc8*8],
                        &As[buf][chunk*512]);
        }
#pragma unroll
        for (int it = 0; it < 2; ++it) {
            int chunk = it*4 + w;
            int row = chunk*16 + srowA;
            int n = bn + row; if (n > N-1) n = N-1;
            gload_lds16(&Wb[(long)n*K + kk + sc8*8],
                        &Bs[buf][chunk*512]);
        }
    };

    f32x4 acc[4][4] = {};
    int nt = K >> 5;
    stage(0, 0);                    // prologue

    for (int t = 0; t < nt; ++t) {
        int cur = t & 1;
        __syncthreads();            // vmcnt(0)+barrier: buf[cur] staged
        if (t + 1 < nt) stage(cur ^ 1, (t + 1) << 5);
        bf16x8 af[4], bfv[4];
#pragma unroll
        for (int mi = 0; mi < 4; ++mi)
            af[mi] = *(const bf16x8*)&As[cur][(wr*64 + mi*16 + lrow)*32 + kg*8];
#pragma unroll
        for (int ni = 0; ni < 4; ++ni)
            bfv[ni] = *(const bf16x8*)&Bs[cur][(wc*64 + ni*16 + lrow)*32 + kg*8];
#pragma unroll
        for (int mi = 0; mi < 4; ++mi)
#pragma unroll
            for (int ni = 0; ni < 4; ++ni)
                acc[mi][ni] = __builtin_amdgcn_mfma_f32_16x16x32_bf16(
                    af[mi], bfv[ni], acc[mi][ni], 0, 0, 0);
    }

    // epilogue: C/D frag mapping col=lane&15, row=(lane>>4)*4+reg
#pragma unroll
    for (int mi = 0; mi < 4; ++mi) {
#pragma unroll
        for (int ni = 0; ni < 4; ++ni) {
            int n = bn + wc*64 + ni*16 + lrow;
            if (n >= N) continue;
#pragma unroll
            for (int reg = 0; reg < 4; ++reg) {
                int m = bm + wr*64 + mi*16 + kg*4 + reg;
                float v = acc[mi][ni][reg];
                if (EPI == 0) {
                    if (n < n_split) {
                        if (bias)  v += bias[n];
                        if (resid) v += resid[(long)m*ldr + n];
                        ((float*)Cv)[(long)m*ldc + n] = v;
                    } else {
                        ((float*)C2v)[(long)m*ldc2 + (n - n_split)] = v;
                    }
                } else if (EPI == 1) {
                    if (n < n_split)
                        ((ushort_t*)Cv)[(long)m*ldc + n] = f2bf(v);
                    else
                        ((ushort_t*)C2v)[(long)m*ldc2 + (n - n_split)] = f2bf(v);
                } else {
                    if (n < n_split) {
                        v += bias[n];
                        float sp = (v > 20.f) ? v : log1pf(__expf(v));
                        ((ushort_t*)Cv)[(long)m*ldc + n] = f2bf(sp);
                    } else {
                        ((float*)C2v)[(long)m*ldc2 + (n - n_split)] = v;
                    }
                }
            }
        }
    }
}

// ---------------------------------------------------------------------------
// Depthwise causal/anti-causal conv + bias + SiLU, ALL batches in one grid.
// bf16 in (xc), bf16 out (u). Conv window clamped to the row's own batch.
__global__ __launch_bounds__(256) void conv_silu(
    const ushort_t* __restrict__ xc, const float* __restrict__ cw,
    const float* __restrict__ cb, ushort_t* __restrict__ ub, int dir)
{
    long idx4 = (long)blockIdx.x * 256 + threadIdx.x;   // BB*LL*DIN/4 total
    int dq  = (int)(idx4 % (DIN/4));
    long row = idx4 / (DIN/4);            // 0 .. BB*LL-1
    int l   = (int)(row % LL);
    long base = row - l;                  // batch start row
    int d   = dq * 4;
    f32x4 acc = *(const f32x4*)&cb[d];
    f32x4 w0 = *(const f32x4*)&cw[(d+0)*CD];
    f32x4 w1 = *(const f32x4*)&cw[(d+1)*CD];
    f32x4 w2 = *(const f32x4*)&cw[(d+2)*CD];
    f32x4 w3 = *(const f32x4*)&cw[(d+3)*CD];
#pragma unroll
    for (int k = 0; k < CD; ++k) {
        int j = dir ? (l + 3 - k) : (l - 3 + k);
        if (j >= 0 && j < LL) {
            u16x4 xv = *(const u16x4*)&xc[(base + j)*DIN + d];
            acc[0] += w0[k]*bf2f(xv[0]);
            acc[1] += w1[k]*bf2f(xv[1]);
            acc[2] += w2[k]*bf2f(xv[2]);
            acc[3] += w3[k]*bf2f(xv[3]);
        }
    }
    u16x4 o;
#pragma unroll
    for (int e = 0; e < 4; ++e)
        o[e] = f2bf(acc[e] / (1.f + __expf(-acc[e])));   // silu
    *(u16x4*)&ub[idx4*4] = o;
}

// ---------------------------------------------------------------------------
// Chunked selective scan, pass 1. Block = 256 thr = 64 d x 4 n-groups
// (4 states/thread). delta is ALREADY softplus'ed bf16 (comb GEMM epilogue).
__global__ __launch_bounds__(256) void scan_pass1(
    const ushort_t* __restrict__ u, const ushort_t* __restrict__ dl,
    const float* __restrict__ bc, const float* __restrict__ A_log,
    float* __restrict__ Pc, float* __restrict__ Sc, int dir)
{
    __shared__ float s_u[CH2][DPB];
    __shared__ float s_dl[CH2][DPB];
    __shared__ float s_B[CH2][16];
    int t = threadIdx.x;
    int d0 = (blockIdx.x % (DIN/DPB)) * DPB;
    int c  = blockIdx.x / (DIN/DPB);
    int scol = (t & 15) * 4;
#pragma unroll
    for (int i = 0; i < 4; ++i) {
        int row = (t >> 4) + i*16;
        int tau = c*CH2 + row;
        int p = dir ? (LL-1-tau) : tau;
        u16x4 uv = *(const u16x4*)&u[(long)p*DIN + d0 + scol];
        u16x4 dv = *(const u16x4*)&dl[(long)p*DIN + d0 + scol];
        f32x4 uf, df;
#pragma unroll
        for (int e = 0; e < 4; ++e) { uf[e] = bf2f(uv[e]); df[e] = bf2f(dv[e]); }
        *(f32x4*)&s_u[row][scol] = uf;
        *(f32x4*)&s_dl[row][scol] = df;
    }
    {
        int row = t >> 2, col = (t & 3)*4;
        int tau = c*CH2 + row;
        int p = dir ? (LL-1-tau) : tau;
        *(f32x4*)&s_B[row][col] = *(const f32x4*)&bc[(long)p*NBC + col];
    }
    __syncthreads();
    int dloc = t >> 2, ng = t & 3;
    int d = d0 + dloc;
    f32x4 Alv = *(const f32x4*)&A_log[d*NST + ng*4];
    float An2[4];
#pragma unroll
    for (int j = 0; j < 4; ++j) An2[j] = -__expf(Alv[j]) * LOG2E;
    float h[4] = {0.f, 0.f, 0.f, 0.f};
    float sumd = 0.f;
#pragma unroll 4
    for (int i = 0; i < CH2; ++i) {
        float delta = s_dl[i][dloc];
        float du = delta * s_u[i][dloc];
        f32x4 Bv = *(const f32x4*)&s_B[i][ng*4];
#pragma unroll
        for (int j = 0; j < 4; ++j)
            h[j] = exp2f(delta*An2[j])*h[j] + du*Bv[j];
        sumd += delta;
    }
    long o = ((long)c*DIN + d)*NST + ng*4;
    f32x4 pv, sv;
#pragma unroll
    for (int j = 0; j < 4; ++j) { pv[j] = exp2f(An2[j]*sumd); sv[j] = h[j]; }
    *(f32x4*)&Pc[o] = pv;
    *(f32x4*)&Sc[o] = sv;
}

// ---------------------------------------------------------------------------
// Chunked scan, mid: exclusive prefix over chunks per (d,n); Hin in place.
__global__ __launch_bounds__(256) void scan_mid(
    float* __restrict__ Pc, const float* __restrict__ Sc)
{
    int idx = blockIdx.x*256 + threadIdx.x;
    if (idx >= DIN*NST) return;
    float h = 0.f;
    for (int c = 0; c < NCH2; ++c) {
        long o = (long)c*DIN*NST + idx;
        float p = Pc[o], s = Sc[o];
        Pc[o] = h;
        h = p*h + s;
    }
}

// ---------------------------------------------------------------------------
// Chunked scan, pass 2: re-run chunk from Hin; fused y+=D*u, y*=silu(z);
// writes gated y bf16. NOTE: zb and yg may ALIAS (y written over z at the
// same element by the same thread after the read) — no __restrict__ here.
__global__ __launch_bounds__(256) void scan_pass2(
    const ushort_t* __restrict__ u, const ushort_t* __restrict__ dl,
    const ushort_t* zb, const float* __restrict__ bc,
    const float* __restrict__ Hin,
    const float* __restrict__ A_log, const float* __restrict__ Dp,
    ushort_t* yg, int dir)
{
    __shared__ float s_u[CH2][DPB];
    __shared__ float s_dl[CH2][DPB];    // delta; y written over it
    __shared__ float s_B[CH2][16];
    __shared__ float s_C[CH2][16];
    int t = threadIdx.x;
    int d0 = (blockIdx.x % (DIN/DPB)) * DPB;
    int c  = blockIdx.x / (DIN/DPB);
    int scol = (t & 15) * 4;
#pragma unroll
    for (int i = 0; i < 4; ++i) {
        int row = (t >> 4) + i*16;
        int tau = c*CH2 + row;
        int p = dir ? (LL-1-tau) : tau;
        u16x4 uv = *(const u16x4*)&u[(long)p*DIN + d0 + scol];
        u16x4 dv = *(const u16x4*)&dl[(long)p*DIN + d0 + scol];
        f32x4 uf, df;
#pragma unroll
        for (int e = 0; e < 4; ++e) { uf[e] = bf2f(uv[e]); df[e] = bf2f(dv[e]); }
        *(f32x4*)&s_u[row][scol] = uf;
        *(f32x4*)&s_dl[row][scol] = df;
    }
    {
        int row = t >> 2, col = (t & 3)*4;
        int tau = c*CH2 + row;
        int p = dir ? (LL-1-tau) : tau;
        *(f32x4*)&s_B[row][col] = *(const f32x4*)&bc[(long)p*NBC + col];
        *(f32x4*)&s_C[row][col] = *(const f32x4*)&bc[(long)p*NBC + NST + col];
    }
    __syncthreads();
    int dloc = t >> 2, ng = t & 3;
    int d = d0 + dloc;
    f32x4 Alv = *(const f32x4*)&A_log[d*NST + ng*4];
    float An2[4];
#pragma unroll
    for (int j = 0; j < 4; ++j) An2[j] = -__expf(Alv[j]) * LOG2E;
    float Dv = Dp[d];
    f32x4 hv = *(const f32x4*)&Hin[((long)c*DIN + d)*NST + ng*4];
    float h[4] = {hv[0], hv[1], hv[2], hv[3]};
#pragma unroll 4
    for (int i = 0; i < CH2; ++i) {
        float delta = s_dl[i][dloc];
        float uv    = s_u[i][dloc];
        float du    = delta * uv;
        f32x4 Bv = *(const f32x4*)&s_B[i][ng*4];
        f32x4 Cv = *(const f32x4*)&s_C[i][ng*4];
        float prod = 0.f;
#pragma unroll
        for (int j = 0; j < 4; ++j) {
            h[j] = exp2f(delta*An2[j])*h[j] + du*Bv[j];
            prod += h[j]*Cv[j];
        }
        prod += __shfl_xor(prod, 1);
        prod += __shfl_xor(prod, 2);
        if (ng == 0) s_dl[i][dloc] = prod + Dv*uv;   // y over dead delta slot
    }
    __syncthreads();
    // gate phase: y *= silu(z), write bf16, coalesced (read z then overwrite)
#pragma unroll
    for (int i = 0; i < 4; ++i) {
        int row = (t >> 4) + i*16;
        int tau = c*CH2 + row;
        int p = dir ? (LL-1-tau) : tau;
        u16x4 z4 = *(const u16x4*)&zb[(long)p*DIN + d0 + scol];
        u16x4 o;
#pragma unroll
        for (int e = 0; e < 4; ++e) {
            float y = s_dl[row][scol + e];
            float z = bf2f(z4[e]);
            o[e] = f2bf(y * z / (1.f + __expf(-z)));
        }
        *(u16x4*)&yg[(long)p*DIN + d0 + scol] = o;
    }
}

// ---------------------------------------------------------------------------
extern "C" void kernel_launch(void* const* d_in, const int* in_sizes, int n_in,
                              void* d_out, int out_size, void* d_ws, size_t ws_size,
                              hipStream_t stream)
{
    const float* x        = (const float*)d_in[0];
    const float* in_w     = (const float*)d_in[1];
    const float* conv_w   = (const float*)d_in[2];
    const float* conv_b   = (const float*)d_in[3];
    const float* xproj_w  = (const float*)d_in[4];
    const float* dt_w     = (const float*)d_in[5];
    const float* dt_b     = (const float*)d_in[6];
    const float* A_log    = (const float*)d_in[7];
    const float* Dp       = (const float*)d_in[8];
    const float* out_w    = (const float*)d_in[9];
    const float* ln_g     = (const float*)d_in[10];
    const float* ln_b     = (const float*)d_in[11];
    const float* fus_w    = (const float*)d_in[12];
    const float* fus_b    = (const float*)d_in[13];
    float* out = (float*)d_out;

    // workspace layout, ~126 MB. f32 first, then bf16.
    // Aliases: dl_all = xc_all (xc dead after conv); yg = z_all (in-place gate).
    float* ws   = (float*)d_ws;
    float* bcb  = ws;                        // 8192*32      =   262,144 f32
    float* Pc   = bcb + (long)BB*LL*NBC;     // 32*1536*16   =   786,432
    float* Sc   = Pc  + (long)NCH2*DIN*NST;  // 32*1536*16   =   786,432
    ushort_t* xn_all = (ushort_t*)(Sc + (long)NCH2*DIN*NST); // 8192*768
    ushort_t* xc_all = xn_all + (long)BB*LL*DD;   // 8192*1536 (= dl_all)
    ushort_t* z_all  = xc_all + (long)BB*LL*DIN;  // 8192*1536 (= yg)
    ushort_t* u_all  = z_all  + (long)BB*LL*DIN;  // 8192*1536
    ushort_t* in_w_bf= u_all  + (long)BB*LL*DIN;  // 2*3072*768
    ushort_t* wdc_bf = in_w_bf+ 2L*2*DIN*DD;      // 2*1568*1536
    ushort_t* wc_bf  = wdc_bf + 2L*NCOMB*DIN;     // 2*768*1536
    ushort_t* owt_bf = wc_bf  + 2L*DD*DIN;        // 2*1536*768
    ushort_t* fus_bf = owt_bf + 2L*DIN*DD;        // 768*1536
    ushort_t* dl_all = xc_all;                    // alias (see above)

    // ---- weight prep (per call, batch-independent) ----
    cvt_bf16<<<(DD*2*DD)/256, 256, 0, stream>>>(fus_w, fus_bf, (long)DD*2*DD);
    for (int dir = 0; dir < 2; ++dir) {
        cvt_bf16<<<(2*DIN*DD)/256, 256, 0, stream>>>(
            in_w + (long)dir*2*DIN*DD, in_w_bf + (long)dir*2*DIN*DD,
            (long)2*DIN*DD);
        wdcat_build<<<(NCOMB*DIN)/256, 256, 0, stream>>>(
            dt_w + (long)dir*DIN*RR, xproj_w + (long)dir*(RR+2*NST)*DIN,
            wdc_bf + (long)dir*NCOMB*DIN);
        owt_cvt<<<(DIN*DD)/256, 256, 0, stream>>>(
            out_w + (long)dir*DD*DIN, owt_bf + (long)dir*DIN*DD);
        // Wc[dir] = fus_w[:, dir*768:+768] @ out_w[dir]  -> bf16 directly
        gemm_mfma<1><<<dim3(12,6), 256, 0, stream>>>(
            fus_bf + dir*DD, owt_bf + (long)dir*DIN*DD, nullptr, nullptr,
            wc_bf + (long)dir*DD*DIN, nullptr,
            DD, DIN, DD, 2*DD, DIN, 0, DIN, 0);
    }

    // LN once for all batches
    ln_kernel<<<BB*LL, 256, 0, stream>>>(x, ln_g, ln_b, xn_all);

    for (int dir = 0; dir < 2; ++dir) {
        // [xc | z] = xn @ in_w[dir].T   (8192 x 3072, K=768) -> bf16 split
        gemm_mfma<1><<<dim3(24,64), 256, 0, stream>>>(
            xn_all, in_w_bf + (long)dir*2*DIN*DD,
            nullptr, nullptr, xc_all, z_all,
            BB*LL, 2*DIN, DD, DD, DIN, 0, DIN, DIN);
        // u = silu(conv(xc) + cb)  -> bf16, all batches
        conv_silu<<<(BB*LL*DIN/4)/256, 256, 0, stream>>>(
            xc_all, conv_w + dir*DIN*CD, conv_b + dir*DIN, u_all, dir);
        // [softplus(delta+dt_b) | B | C] = u @ Wcomb.T  (8192x1568, K=1536)
        // dl_all aliases xc_all (dead after conv)
        gemm_mfma<2><<<dim3(13,64), 256, 0, stream>>>(
            u_all, wdc_bf + (long)dir*NCOMB*DIN, dt_b + dir*DIN, nullptr,
            dl_all, bcb, BB*LL, NCOMB, DIN, DIN, DIN, 0, DIN, NBC);
        // chunked selective scan, per batch; yg written in place over z
        for (int b = 0; b < BB; ++b) {
            long ro = (long)b*LL;
            scan_pass1<<<(DIN/DPB)*NCH2, 256, 0, stream>>>(
                u_all + ro*DIN, dl_all + ro*DIN, bcb + ro*NBC,
                A_log + (long)dir*DIN*NST, Pc, Sc, dir);
            scan_mid<<<(DIN*NST)/256, 256, 0, stream>>>(Pc, Sc);
            scan_pass2<<<(DIN/DPB)*NCH2, 256, 0, stream>>>(
                u_all + ro*DIN, dl_all + ro*DIN, z_all + ro*DIN, bcb + ro*NBC,
                Pc, A_log + (long)dir*DIN*NST, Dp + dir*DIN,
                z_all + ro*DIN, dir);
        }
        // merged out-GEMM over all batches: M=8192 (A = gated y in z_all)
        if (dir == 0) {
            gemm_mfma<0><<<dim3(6,64), 256, 0, stream>>>(
                z_all, wc_bf, fus_b, x,
                out, nullptr, BB*LL, DD, DIN, DIN, DD, DD, DD, 0);
        } else {
            gemm_mfma<0><<<dim3(6,64), 256, 0, stream>>>(
                z_all, wc_bf + (long)DD*DIN, nullptr, out,
                out, nullptr, BB*LL, DD, DIN, DIN, DD, DD, DD, 0);
        }
    }
}

// Round 10
// 869.670 us; speedup vs baseline: 12.2934x; 1.1634x over previous
//
#include <hip/hip_runtime.h>
#include <hip/hip_bf16.h>

// Problem constants
#define BB 4
#define LL 2048
#define DD 768
#define DIN 1536
#define NST 16
#define CD 4
#define RR 48
#define NBC 32          // B,C columns (2*NST)
#define NCOMB (DIN+NBC) // 1568: combined [delta | B | C] GEMM width
#define CH2 64          // scan chunk length
#define NCH2 (LL/CH2)   // 32 chunks
#define DPB 64          // d-channels per scan block
#define LOG2E 1.44269504088896f

typedef unsigned short ushort_t;
typedef unsigned int u32;
typedef __attribute__((ext_vector_type(4))) float f32x4;
typedef __attribute__((ext_vector_type(8))) short bf16x8;
typedef __attribute__((ext_vector_type(4))) ushort_t u16x4;

static __device__ __forceinline__ ushort_t f2bf(float f) {
    unsigned int u = __float_as_uint(f);
    u += 0x7FFF + ((u >> 16) & 1);          // RNE
    return (ushort_t)(u >> 16);
}
static __device__ __forceinline__ float bf2f(ushort_t h) {
    return __uint_as_float(((u32)h) << 16);
}

static __device__ __forceinline__ void gload_lds16(const void* g, void* l) {
    __builtin_amdgcn_global_load_lds(
        (const __attribute__((address_space(1))) u32*)g,
        (__attribute__((address_space(3))) u32*)l, 16, 0, 0);
}

// ---------------------------------------------------------------------------
// LayerNorm over last dim (768). One block (256 thr) per row, ALL batches.
__global__ __launch_bounds__(256) void ln_kernel(
    const float* __restrict__ x, const float* __restrict__ g,
    const float* __restrict__ b, ushort_t* __restrict__ xn)
{
    int row = blockIdx.x;
    const float* xr = x + (long)row * DD;
    int t = threadIdx.x;
    float v[3];
    float s = 0.f;
#pragma unroll
    for (int i = 0; i < 3; ++i) { v[i] = xr[t + i*256]; s += v[i]; }
#pragma unroll
    for (int off = 32; off >= 1; off >>= 1) s += __shfl_xor(s, off);
    __shared__ float red[4], red2[4];
    int wid = t >> 6;
    if ((t & 63) == 0) red[wid] = s;
    __syncthreads();
    float mean = (red[0]+red[1]+red[2]+red[3]) * (1.f/768.f);
    float vs = 0.f;
#pragma unroll
    for (int i = 0; i < 3; ++i) { float d0 = v[i]-mean; vs += d0*d0; }
#pragma unroll
    for (int off = 32; off >= 1; off >>= 1) vs += __shfl_xor(vs, off);
    if ((t & 63) == 0) red2[wid] = vs;
    __syncthreads();
    float var = (red2[0]+red2[1]+red2[2]+red2[3]) * (1.f/768.f);
    float rstd = rsqrtf(var + 1e-5f);
    ushort_t* xo = xn + (long)row * DD;
#pragma unroll
    for (int i = 0; i < 3; ++i) {
        int c = t + i*256;
        xo[c] = f2bf((v[i]-mean)*rstd*g[c] + b[c]);
    }
}

// ---------------------------------------------------------------------------
// elementwise f32 -> bf16 convert
__global__ __launch_bounds__(256) void cvt_bf16(
    const float* __restrict__ in, ushort_t* __restrict__ out, long n)
{
    long i = (long)blockIdx.x*256 + threadIdx.x;
    if (i < n) out[i] = f2bf(in[i]);
}

// ---------------------------------------------------------------------------
// transpose-convert out_w (2 x DD x DIN) -> owt (2 x DIN x DD) bf16, both dirs
__global__ __launch_bounds__(256) void owt_cvt(
    const float* __restrict__ ow, ushort_t* __restrict__ out)
{
    long idx = (long)blockIdx.x*256 + threadIdx.x;
    if (idx >= 2L*DIN*DD) return;
    long dir = idx / ((long)DIN*DD);
    long r   = idx % ((long)DIN*DD);
    int k = (int)(r % DD);   // source row
    int n = (int)(r / DD);   // source col
    out[idx] = f2bf(ow[dir*DD*DIN + (long)k*DIN + n]);
}

// ---------------------------------------------------------------------------
// Build combined [Wdc | xw_B | xw_C] bf16 weight (2 x NCOMB x DIN), both dirs
__global__ __launch_bounds__(256) void wdcat_build(
    const float* __restrict__ dt_w, const float* __restrict__ xw,
    ushort_t* __restrict__ out)
{
    long idx = (long)blockIdx.x*256 + threadIdx.x;
    if (idx >= 2L*NCOMB*DIN) return;
    long dir = idx / ((long)NCOMB*DIN);
    long r   = idx % ((long)NCOMB*DIN);
    int k = (int)(r % DIN);
    int d = (int)(r / DIN);
    const float* dw = dt_w + dir*DIN*RR;
    const float* xwp = xw + dir*(long)(RR+2*NST)*DIN;
    float acc;
    if (d < DIN) {
        acc = 0.f;
#pragma unroll 8
        for (int rr = 0; rr < RR; ++rr)
            acc += dw[d*RR + rr] * xwp[(long)rr*DIN + k];
    } else {
        acc = xwp[(long)(RR + d - DIN)*DIN + k];
    }
    out[idx] = f2bf(acc);
}

// ---------------------------------------------------------------------------
// MFMA GEMM, bf16 x bf16 -> f32 acc. Double-buffered LDS, one barrier/K-step.
// XCD-aware swizzle: grid size MUST be a multiple of 8.
// Epilogue variants:
//  EPI=0: C f32 (+bias +resid), C2 f32
//  EPI=1: C bf16 (plain),       C2 bf16
//  EPI=2: C bf16 softplus(v+bias), C2 f32   (comb GEMM: delta | B,C)
template<int EPI>
__global__ __launch_bounds__(256) void gemm_mfma(
    const ushort_t* __restrict__ A, const ushort_t* __restrict__ Wb,
    const float* __restrict__ bias, const float* __restrict__ resid,
    void* __restrict__ Cv, void* __restrict__ C2v,
    int M, int N, int K, int lda, int ldc, int ldr, int n_split, int ldc2)
{
    __shared__ __attribute__((aligned(16))) ushort_t As[2][128*32];
    __shared__ __attribute__((aligned(16))) ushort_t Bs[2][128*32];
    int tid = threadIdx.x;
    // XCD swizzle: consecutive logical tiles -> same XCD (bijective, nwg%8==0)
    int gx = gridDim.x;
    int nwg = gx * gridDim.y;
    int flat = blockIdx.y * gx + blockIdx.x;
    int L = (flat & 7) * (nwg >> 3) + (flat >> 3);
    int bm = (L / gx) * 128, bn = (L % gx) * 128;
    int lane = tid & 63, w = tid >> 6;
    int wr = w >> 1, wc = w & 1;
    int lrow = lane & 15, kg = lane >> 4;
    int srowA = lane >> 2;          // 0..15 within chunk
    int sc8  = lane & 3;            // 16B slot within 64B row

    auto stage = [&](int buf, int kk) {
#pragma unroll
        for (int it = 0; it < 2; ++it) {
            int chunk = it*4 + w;                  // 0..7 (wave-uniform)
            int row = chunk*16 + srowA;            // 0..127
            gload_lds16(&A[(long)(bm+row)*lda + kk + sc8*8],
                        &As[buf][chunk*512]);
        }
#pragma unroll
        for (int it = 0; it < 2; ++it) {
            int chunk = it*4 + w;
            int row = chunk*16 + srowA;
            int n = bn + row; if (n > N-1) n = N-1;
            gload_lds16(&Wb[(long)n*K + kk + sc8*8],
                        &Bs[buf][chunk*512]);
        }
    };

    f32x4 acc[4][4] = {};
    int nt = K >> 5;
    stage(0, 0);                    // prologue

    for (int t = 0; t < nt; ++t) {
        int cur = t & 1;
        __syncthreads();            // vmcnt(0)+barrier: buf[cur] staged
        if (t + 1 < nt) stage(cur ^ 1, (t + 1) << 5);
        bf16x8 af[4], bfv[4];
#pragma unroll
        for (int mi = 0; mi < 4; ++mi)
            af[mi] = *(const bf16x8*)&As[cur][(wr*64 + mi*16 + lrow)*32 + kg*8];
#pragma unroll
        for (int ni = 0; ni < 4; ++ni)
            bfv[ni] = *(const bf16x8*)&Bs[cur][(wc*64 + ni*16 + lrow)*32 + kg*8];
#pragma unroll
        for (int mi = 0; mi < 4; ++mi)
#pragma unroll
            for (int ni = 0; ni < 4; ++ni)
                acc[mi][ni] = __builtin_amdgcn_mfma_f32_16x16x32_bf16(
                    af[mi], bfv[ni], acc[mi][ni], 0, 0, 0);
    }

    // epilogue: C/D frag mapping col=lane&15, row=(lane>>4)*4+reg
#pragma unroll
    for (int mi = 0; mi < 4; ++mi) {
#pragma unroll
        for (int ni = 0; ni < 4; ++ni) {
            int n = bn + wc*64 + ni*16 + lrow;
            if (n >= N) continue;
#pragma unroll
            for (int reg = 0; reg < 4; ++reg) {
                int m = bm + wr*64 + mi*16 + kg*4 + reg;
                float v = acc[mi][ni][reg];
                if (EPI == 0) {
                    if (n < n_split) {
                        if (bias)  v += bias[n];
                        if (resid) v += resid[(long)m*ldr + n];
                        ((float*)Cv)[(long)m*ldc + n] = v;
                    } else {
                        ((float*)C2v)[(long)m*ldc2 + (n - n_split)] = v;
                    }
                } else if (EPI == 1) {
                    if (n < n_split)
                        ((ushort_t*)Cv)[(long)m*ldc + n] = f2bf(v);
                    else
                        ((ushort_t*)C2v)[(long)m*ldc2 + (n - n_split)] = f2bf(v);
                } else {
                    if (n < n_split) {
                        v += bias[n];
                        // fast softplus: output is bf16 (0.4% quantum), __logf ok
                        float sp = (v > 20.f) ? v : __logf(1.f + __expf(v));
                        ((ushort_t*)Cv)[(long)m*ldc + n] = f2bf(sp);
                    } else {
                        ((float*)C2v)[(long)m*ldc2 + (n - n_split)] = v;
                    }
                }
            }
        }
    }
}

// ---------------------------------------------------------------------------
// Depthwise causal/anti-causal conv + bias + SiLU, ALL batches in one grid.
// bf16 in (xc), bf16 out (u). Conv window clamped to the row's own batch.
__global__ __launch_bounds__(256) void conv_silu(
    const ushort_t* __restrict__ xc, const float* __restrict__ cw,
    const float* __restrict__ cb, ushort_t* __restrict__ ub, int dir)
{
    long idx4 = (long)blockIdx.x * 256 + threadIdx.x;   // BB*LL*DIN/4 total
    int dq  = (int)(idx4 % (DIN/4));
    long row = idx4 / (DIN/4);            // 0 .. BB*LL-1
    int l   = (int)(row % LL);
    long base = row - l;                  // batch start row
    int d   = dq * 4;
    f32x4 acc = *(const f32x4*)&cb[d];
    f32x4 w0 = *(const f32x4*)&cw[(d+0)*CD];
    f32x4 w1 = *(const f32x4*)&cw[(d+1)*CD];
    f32x4 w2 = *(const f32x4*)&cw[(d+2)*CD];
    f32x4 w3 = *(const f32x4*)&cw[(d+3)*CD];
#pragma unroll
    for (int k = 0; k < CD; ++k) {
        int j = dir ? (l + 3 - k) : (l - 3 + k);
        if (j >= 0 && j < LL) {
            u16x4 xv = *(const u16x4*)&xc[(base + j)*DIN + d];
            acc[0] += w0[k]*bf2f(xv[0]);
            acc[1] += w1[k]*bf2f(xv[1]);
            acc[2] += w2[k]*bf2f(xv[2]);
            acc[3] += w3[k]*bf2f(xv[3]);
        }
    }
    u16x4 o;
#pragma unroll
    for (int e = 0; e < 4; ++e)
        o[e] = f2bf(acc[e] / (1.f + __expf(-acc[e])));   // silu
    *(u16x4*)&ub[idx4*4] = o;
}

// ---------------------------------------------------------------------------
// Chunked selective scan, pass 1, ALL batches. Block = 256 thr = 64 d x 4
// n-groups (4 states/thread). delta ALREADY softplus'ed bf16 (comb epilogue).
// Grid = BB * (DIN/DPB) * NCH2.
__global__ __launch_bounds__(256) void scan_pass1(
    const ushort_t* __restrict__ u, const ushort_t* __restrict__ dl,
    const float* __restrict__ bc, const float* __restrict__ A_log,
    float* __restrict__ Pc, float* __restrict__ Sc, int dir)
{
    __shared__ float s_u[CH2][DPB];
    __shared__ float s_dl[CH2][DPB];
    __shared__ float s_B[CH2][16];
    int t = threadIdx.x;
    const int bpg = (DIN/DPB)*NCH2;       // 768 blocks per batch
    int b   = blockIdx.x / bpg;
    int rem = blockIdx.x % bpg;
    int d0  = (rem % (DIN/DPB)) * DPB;
    int c   = rem / (DIN/DPB);
    long ro = (long)b*LL;
    int scol = (t & 15) * 4;
#pragma unroll
    for (int i = 0; i < 4; ++i) {
        int row = (t >> 4) + i*16;
        int tau = c*CH2 + row;
        int p = dir ? (LL-1-tau) : tau;
        u16x4 uv = *(const u16x4*)&u[(ro+p)*DIN + d0 + scol];
        u16x4 dv = *(const u16x4*)&dl[(ro+p)*DIN + d0 + scol];
        f32x4 uf, df;
#pragma unroll
        for (int e = 0; e < 4; ++e) { uf[e] = bf2f(uv[e]); df[e] = bf2f(dv[e]); }
        *(f32x4*)&s_u[row][scol] = uf;
        *(f32x4*)&s_dl[row][scol] = df;
    }
    {
        int row = t >> 2, col = (t & 3)*4;
        int tau = c*CH2 + row;
        int p = dir ? (LL-1-tau) : tau;
        *(f32x4*)&s_B[row][col] = *(const f32x4*)&bc[(ro+p)*NBC + col];
    }
    __syncthreads();
    int dloc = t >> 2, ng = t & 3;
    int d = d0 + dloc;
    f32x4 Alv = *(const f32x4*)&A_log[d*NST + ng*4];
    float An2[4];
#pragma unroll
    for (int j = 0; j < 4; ++j) An2[j] = -__expf(Alv[j]) * LOG2E;
    float h[4] = {0.f, 0.f, 0.f, 0.f};
    float sumd = 0.f;
#pragma unroll 4
    for (int i = 0; i < CH2; ++i) {
        float delta = s_dl[i][dloc];
        float du = delta * s_u[i][dloc];
        f32x4 Bv = *(const f32x4*)&s_B[i][ng*4];
#pragma unroll
        for (int j = 0; j < 4; ++j)
            h[j] = exp2f(delta*An2[j])*h[j] + du*Bv[j];
        sumd += delta;
    }
    long o = (((long)b*NCH2 + c)*DIN + d)*NST + ng*4;
    f32x4 pv, sv;
#pragma unroll
    for (int j = 0; j < 4; ++j) { pv[j] = exp2f(An2[j]*sumd); sv[j] = h[j]; }
    *(f32x4*)&Pc[o] = pv;
    *(f32x4*)&Sc[o] = sv;
}

// ---------------------------------------------------------------------------
// Chunked scan, mid: exclusive prefix over chunks per (b,d,n); Hin in place.
__global__ __launch_bounds__(256) void scan_mid(
    float* __restrict__ Pc, const float* __restrict__ Sc)
{
    int idx = blockIdx.x*256 + threadIdx.x;
    if (idx >= BB*DIN*NST) return;
    int b  = idx / (DIN*NST);
    int dn = idx % (DIN*NST);
    float h = 0.f;
    for (int c = 0; c < NCH2; ++c) {
        long o = ((long)b*NCH2 + c)*DIN*NST + dn;
        float p = Pc[o], s = Sc[o];
        Pc[o] = h;
        h = p*h + s;
    }
}

// ---------------------------------------------------------------------------
// Chunked scan, pass 2, ALL batches: re-run chunk from Hin; fused y+=D*u,
// y*=silu(z); writes gated y bf16. zb/yg may ALIAS (same-thread same-element
// read-then-write) — no __restrict__ on them.
__global__ __launch_bounds__(256) void scan_pass2(
    const ushort_t* __restrict__ u, const ushort_t* __restrict__ dl,
    const ushort_t* zb, const float* __restrict__ bc,
    const float* __restrict__ Hin,
    const float* __restrict__ A_log, const float* __restrict__ Dp,
    ushort_t* yg, int dir)
{
    __shared__ float s_u[CH2][DPB];
    __shared__ float s_dl[CH2][DPB];    // delta; y written over it
    __shared__ float s_B[CH2][16];
    __shared__ float s_C[CH2][16];
    int t = threadIdx.x;
    const int bpg = (DIN/DPB)*NCH2;
    int b   = blockIdx.x / bpg;
    int rem = blockIdx.x % bpg;
    int d0  = (rem % (DIN/DPB)) * DPB;
    int c   = rem / (DIN/DPB);
    long ro = (long)b*LL;
    int scol = (t & 15) * 4;
#pragma unroll
    for (int i = 0; i < 4; ++i) {
        int row = (t >> 4) + i*16;
        int tau = c*CH2 + row;
        int p = dir ? (LL-1-tau) : tau;
        u16x4 uv = *(const u16x4*)&u[(ro+p)*DIN + d0 + scol];
        u16x4 dv = *(const u16x4*)&dl[(ro+p)*DIN + d0 + scol];
        f32x4 uf, df;
#pragma unroll
        for (int e = 0; e < 4; ++e) { uf[e] = bf2f(uv[e]); df[e] = bf2f(dv[e]); }
        *(f32x4*)&s_u[row][scol] = uf;
        *(f32x4*)&s_dl[row][scol] = df;
    }
    {
        int row = t >> 2, col = (t & 3)*4;
        int tau = c*CH2 + row;
        int p = dir ? (LL-1-tau) : tau;
        *(f32x4*)&s_B[row][col] = *(const f32x4*)&bc[(ro+p)*NBC + col];
        *(f32x4*)&s_C[row][col] = *(const f32x4*)&bc[(ro+p)*NBC + NST + col];
    }
    __syncthreads();
    int dloc = t >> 2, ng = t & 3;
    int d = d0 + dloc;
    f32x4 Alv = *(const f32x4*)&A_log[d*NST + ng*4];
    float An2[4];
#pragma unroll
    for (int j = 0; j < 4; ++j) An2[j] = -__expf(Alv[j]) * LOG2E;
    float Dv = Dp[d];
    f32x4 hv = *(const f32x4*)&Hin[(((long)b*NCH2 + c)*DIN + d)*NST + ng*4];
    float h[4] = {hv[0], hv[1], hv[2], hv[3]};
#pragma unroll 4
    for (int i = 0; i < CH2; ++i) {
        float delta = s_dl[i][dloc];
        float uv    = s_u[i][dloc];
        float du    = delta * uv;
        f32x4 Bv = *(const f32x4*)&s_B[i][ng*4];
        f32x4 Cv = *(const f32x4*)&s_C[i][ng*4];
        float prod = 0.f;
#pragma unroll
        for (int j = 0; j < 4; ++j) {
            h[j] = exp2f(delta*An2[j])*h[j] + du*Bv[j];
            prod += h[j]*Cv[j];
        }
        prod += __shfl_xor(prod, 1);
        prod += __shfl_xor(prod, 2);
        if (ng == 0) s_dl[i][dloc] = prod + Dv*uv;   // y over dead delta slot
    }
    __syncthreads();
    // gate phase: y *= silu(z), write bf16, coalesced (read z then overwrite)
#pragma unroll
    for (int i = 0; i < 4; ++i) {
        int row = (t >> 4) + i*16;
        int tau = c*CH2 + row;
        int p = dir ? (LL-1-tau) : tau;
        u16x4 z4 = *(const u16x4*)&zb[(ro+p)*DIN + d0 + scol];
        u16x4 o;
#pragma unroll
        for (int e = 0; e < 4; ++e) {
            float y = s_dl[row][scol + e];
            float z = bf2f(z4[e]);
            o[e] = f2bf(y * z / (1.f + __expf(-z)));
        }
        *(u16x4*)&yg[(ro+p)*DIN + d0 + scol] = o;
    }
}

// ---------------------------------------------------------------------------
extern "C" void kernel_launch(void* const* d_in, const int* in_sizes, int n_in,
                              void* d_out, int out_size, void* d_ws, size_t ws_size,
                              hipStream_t stream)
{
    const float* x        = (const float*)d_in[0];
    const float* in_w     = (const float*)d_in[1];
    const float* conv_w   = (const float*)d_in[2];
    const float* conv_b   = (const float*)d_in[3];
    const float* xproj_w  = (const float*)d_in[4];
    const float* dt_w     = (const float*)d_in[5];
    const float* dt_b     = (const float*)d_in[6];
    const float* A_log    = (const float*)d_in[7];
    const float* Dp       = (const float*)d_in[8];
    const float* out_w    = (const float*)d_in[9];
    const float* ln_g     = (const float*)d_in[10];
    const float* ln_b     = (const float*)d_in[11];
    const float* fus_w    = (const float*)d_in[12];
    const float* fus_b    = (const float*)d_in[13];
    float* out = (float*)d_out;

    // workspace layout, ~138 MB. f32 first, then bf16.
    // Aliases: dl_all = xc_all (xc dead after conv); yg = z_all (in-place
    // gate); fus_bf -> xc_all region, owt_bf -> u_all region (prep-time only,
    // dead before first activation write).
    float* ws   = (float*)d_ws;
    float* bcb  = ws;                        // 8192*32        = 262,144 f32
    float* Pc   = bcb + (long)BB*LL*NBC;     // 4*32*1536*16   = 3,145,728
    float* Sc   = Pc  + (long)BB*NCH2*DIN*NST;
    ushort_t* xn_all = (ushort_t*)(Sc + (long)BB*NCH2*DIN*NST); // 8192*768
    ushort_t* xc_all = xn_all + (long)BB*LL*DD;   // 8192*1536 (= dl_all)
    ushort_t* z_all  = xc_all + (long)BB*LL*DIN;  // 8192*1536 (= yg)
    ushort_t* u_all  = z_all  + (long)BB*LL*DIN;  // 8192*1536
    ushort_t* in_w_bf= u_all  + (long)BB*LL*DIN;  // 2*3072*768
    ushort_t* wdc_bf = in_w_bf+ 2L*2*DIN*DD;      // 2*1568*1536
    ushort_t* wc_bf  = wdc_bf + 2L*NCOMB*DIN;     // 2*768*1536
    ushort_t* dl_all = xc_all;                    // alias
    ushort_t* fus_bf = xc_all;                    // alias (prep only)
    ushort_t* owt_bf = u_all;                     // alias (prep only)

    // ---- weight prep (per call, batch-independent) ----
    cvt_bf16<<<(DD*2*DD)/256, 256, 0, stream>>>(fus_w, fus_bf, (long)DD*2*DD);
    cvt_bf16<<<(2*2*DIN*DD)/256, 256, 0, stream>>>(in_w, in_w_bf,
                                                   2L*2*DIN*DD);
    wdcat_build<<<(2*NCOMB*DIN)/256, 256, 0, stream>>>(dt_w, xproj_w, wdc_bf);
    owt_cvt<<<(2*DIN*DD)/256, 256, 0, stream>>>(out_w, owt_bf);
    for (int dir = 0; dir < 2; ++dir) {
        // Wc[dir] = fus_w[:, dir*768:+768] @ out_w[dir]  -> bf16 directly
        gemm_mfma<1><<<dim3(12,6), 256, 0, stream>>>(
            fus_bf + dir*DD, owt_bf + (long)dir*DIN*DD, nullptr, nullptr,
            wc_bf + (long)dir*DD*DIN, nullptr,
            DD, DIN, DD, 2*DD, DIN, 0, DIN, 0);
    }

    // LN once for all batches (xn_all distinct from prep aliases)
    ln_kernel<<<BB*LL, 256, 0, stream>>>(x, ln_g, ln_b, xn_all);

    for (int dir = 0; dir < 2; ++dir) {
        // [xc | z] = xn @ in_w[dir].T   (8192 x 3072, K=768) -> bf16 split
        gemm_mfma<1><<<dim3(24,64), 256, 0, stream>>>(
            xn_all, in_w_bf + (long)dir*2*DIN*DD,
            nullptr, nullptr, xc_all, z_all,
            BB*LL, 2*DIN, DD, DD, DIN, 0, DIN, DIN);
        // u = silu(conv(xc) + cb)  -> bf16, all batches
        conv_silu<<<(BB*LL*DIN/4)/256, 256, 0, stream>>>(
            xc_all, conv_w + dir*DIN*CD, conv_b + dir*DIN, u_all, dir);
        // [softplus(delta+dt_b) | B | C] = u @ Wcomb.T  (8192x1568, K=1536)
        gemm_mfma<2><<<dim3(13,64), 256, 0, stream>>>(
            u_all, wdc_bf + (long)dir*NCOMB*DIN, dt_b + dir*DIN, nullptr,
            dl_all, bcb, BB*LL, NCOMB, DIN, DIN, DIN, 0, DIN, NBC);
        // chunked selective scan over ALL batches; yg written in place over z
        scan_pass1<<<BB*(DIN/DPB)*NCH2, 256, 0, stream>>>(
            u_all, dl_all, bcb, A_log + (long)dir*DIN*NST, Pc, Sc, dir);
        scan_mid<<<(BB*DIN*NST)/256, 256, 0, stream>>>(Pc, Sc);
        scan_pass2<<<BB*(DIN/DPB)*NCH2, 256, 0, stream>>>(
            u_all, dl_all, z_all, bcb, Pc, A_log + (long)dir*DIN*NST,
            Dp + dir*DIN, z_all, dir);
        // merged out-GEMM over all batches: M=8192 (A = gated y in z_all)
        if (dir == 0) {
            gemm_mfma<0><<<dim3(6,64), 256, 0, stream>>>(
                z_all, wc_bf, fus_b, x,
                out, nullptr, BB*LL, DD, DIN, DIN, DD, DD, DD, 0);
        } else {
            gemm_mfma<0><<<dim3(6,64), 256, 0, stream>>>(
                z_all, wc_bf + (long)DD*DIN, nullptr, out,
                out, nullptr, BB*LL, DD, DIN, DIN, DD, DD, DD, 0);
        }
    }
}